// Round 6
// baseline (3934.158 us; speedup 1.0000x reference)
//
#include <hip/hip_runtime.h>
#include <hip/hip_bf16.h>

#define U_N 200000
#define I_N 100000
#define G_N 10000
#define B_N 8192
#define NHG (U_N + G_N)   /* 210000 */
#define GG_K 10000
#define GG_KC 313         /* ceil(10000/32) k-chunks */
#define GG_STRIPES 157    /* ceil(10000/64) row stripes */

#define BUCK_SHIFT 8
#define BUCK_ROWS 256
#define NBUCK 821         /* ceil(NHG/256) */
#define ACHUNK 12288      /* edges per partition block */

typedef __attribute__((ext_vector_type(8))) short bf16x8;
typedef __attribute__((ext_vector_type(4))) float f32x4;

static __device__ __forceinline__ float sigmoidf_(float x) {
    return 1.0f / (1.0f + __expf(-x));
}

// f32 -> bf16 bits, round-to-nearest-even
static __device__ __forceinline__ short bfc(float x) {
    unsigned u = __float_as_uint(x);
    unsigned r = (u + 0x7fffu + ((u >> 16) & 1u)) >> 16;
    return (short)r;
}

// ---------------- generic scan kernels ----------------

__global__ void k_scan_partial(const int* __restrict__ in, int* __restrict__ out,
                               int* __restrict__ bsums, int n) {
    __shared__ int sh[256];
    int tid = threadIdx.x;
    int base = blockIdx.x * 1024 + tid * 4;
    int v0 = (base + 0 < n) ? in[base + 0] : 0;
    int v1 = (base + 1 < n) ? in[base + 1] : 0;
    int v2 = (base + 2 < n) ? in[base + 2] : 0;
    int v3 = (base + 3 < n) ? in[base + 3] : 0;
    int s = v0 + v1 + v2 + v3;
    sh[tid] = s;
    __syncthreads();
    for (int off = 1; off < 256; off <<= 1) {
        int t = (tid >= off) ? sh[tid - off] : 0;
        __syncthreads();
        if (tid >= off) sh[tid] += t;
        __syncthreads();
    }
    int excl = sh[tid] - s;
    if (tid == 255) bsums[blockIdx.x] = sh[255];
    if (base + 0 < n) out[base + 0] = excl; excl += v0;
    if (base + 1 < n) out[base + 1] = excl; excl += v1;
    if (base + 2 < n) out[base + 2] = excl; excl += v2;
    if (base + 3 < n) out[base + 3] = excl;
}

__global__ void k_scan_sums(int* bsums, int nb) {  // nb <= 256, single block
    __shared__ int sh[256];
    int tid = threadIdx.x;
    int v = (tid < nb) ? bsums[tid] : 0;
    sh[tid] = v;
    __syncthreads();
    for (int off = 1; off < 256; off <<= 1) {
        int t = (tid >= off) ? sh[tid - off] : 0;
        __syncthreads();
        if (tid >= off) sh[tid] += t;
        __syncthreads();
    }
    if (tid < nb) bsums[tid] = sh[tid] - v;  // exclusive
}

__global__ void k_scan_add(int* out, const int* __restrict__ bsums, int n) {
    int base = blockIdx.x * 1024 + threadIdx.x * 4;
    int add = bsums[blockIdx.x];
#pragma unroll
    for (int j = 0; j < 4; ++j)
        if (base + j < n) out[base + j] += add;
}

// ---------------- atomic-free bucket partition ----------------
// M[bucket * nblk + blk] = count of edges in (blk-chunk, bucket); later scanned.

__global__ void k_bhist(const int* __restrict__ rows, int* __restrict__ M,
                        int nE, int nblk) {
    __shared__ int h[NBUCK];
    for (int i = threadIdx.x; i < NBUCK; i += 256) h[i] = 0;
    __syncthreads();
    int base = blockIdx.x * ACHUNK;
    int end = base + ACHUNK; if (end > nE) end = nE;
    for (int e = base + threadIdx.x; e < end; e += 256)
        atomicAdd(&h[rows[e] >> BUCK_SHIFT], 1);
    __syncthreads();
    for (int b = threadIdx.x; b < NBUCK; b += 256)
        M[(size_t)b * nblk + blockIdx.x] = h[b];
}

// pack: (row & 255) << 24 | col  (col < 2^24), val bits in .y
__global__ void k_bscatter(const int* __restrict__ rows, const int* __restrict__ cols,
                           const float* __restrict__ vals, const int* __restrict__ M,
                           int2* __restrict__ bpair, int nE, int nblk) {
    __shared__ int base[NBUCK];
    for (int i = threadIdx.x; i < NBUCK; i += 256)
        base[i] = M[(size_t)i * nblk + blockIdx.x];
    __syncthreads();
    int s = blockIdx.x * ACHUNK;
    int end = s + ACHUNK; if (end > nE) end = nE;
    for (int e = s + threadIdx.x; e < end; e += 256) {
        int r = rows[e];
        int b = r >> BUCK_SHIFT;
        int pos = atomicAdd(&base[b], 1);  // LDS atomic, fast
        bpair[pos] = make_int2(((r & (BUCK_ROWS - 1)) << 24) | cols[e],
                               __float_as_int(vals[e]));
    }
}

// ---------------- SpMM over buckets, LDS f32 accumulation ----------------
// one block per bucket; 8 waves; lane = dim; sacc[256 rows][64 dims]
__global__ __launch_bounds__(512) void k_spmm_lds(const int* __restrict__ M, int nblk,
                                                  const int2* __restrict__ bpair,
                                                  const __hip_bfloat16* __restrict__ x,
                                                  __hip_bfloat16* __restrict__ out, int nE) {
    __shared__ float sacc[BUCK_ROWS * 64];
    const int b = blockIdx.x;
    for (int i = threadIdx.x; i < BUCK_ROWS * 64; i += 512) sacc[i] = 0.f;
    const int s  = M[(size_t)b * nblk];
    const int e_ = (b + 1 < NBUCK) ? M[(size_t)(b + 1) * nblk] : nE;
    __syncthreads();
    const int lane = threadIdx.x & 63;
    const int w = threadIdx.x >> 6;  // 0..7
    int e = s + w;
    for (; e + 8 < e_; e += 16) {
        int2 p0 = bpair[e];
        int2 p1 = bpair[e + 8];
        unsigned pk0 = (unsigned)p0.x, pk1 = (unsigned)p1.x;
        float x0 = __bfloat162float(x[(size_t)(pk0 & 0xFFFFFF) * 64 + lane]);
        float x1 = __bfloat162float(x[(size_t)(pk1 & 0xFFFFFF) * 64 + lane]);
        atomicAdd(&sacc[(pk0 >> 24) * 64 + lane], __int_as_float(p0.y) * x0);
        atomicAdd(&sacc[(pk1 >> 24) * 64 + lane], __int_as_float(p1.y) * x1);
    }
    if (e < e_) {
        int2 p0 = bpair[e];
        unsigned pk0 = (unsigned)p0.x;
        float x0 = __bfloat162float(x[(size_t)(pk0 & 0xFFFFFF) * 64 + lane]);
        atomicAdd(&sacc[(pk0 >> 24) * 64 + lane], __int_as_float(p0.y) * x0);
    }
    __syncthreads();
    const int gbase = b << BUCK_SHIFT;
    for (int r = w; r < BUCK_ROWS; r += 8) {
        int gr = gbase + r;
        if (gr < NHG)
            out[(size_t)gr * 64 + lane] = __float2bfloat16(sacc[r * 64 + lane]);
    }
}

// ---------------- gi spmm: ballot-batched edge-parallel atomic ----------------
__global__ void k_gi_spmm(const int* __restrict__ rows, const int* __restrict__ cols,
                          const float* __restrict__ vals, const float* __restrict__ ge,
                          const float* __restrict__ ie, float* __restrict__ out, int nE) {
    int lane = threadIdx.x & 63;
    long wslot = blockIdx.x * 4 + (threadIdx.x >> 6);
    const long nslots = 2048 * 4;
    for (long base = wslot * 64; base < nE; base += nslots * 64) {
        long e = base + lane;
        int r = (e < nE) ? rows[e] : 0x7fffffff;
        bool ok = (r < G_N);
        int c = 0;
        float v = 0.f;
        if (ok) { c = cols[e]; v = vals[e]; }
        unsigned long long mask = __ballot(ok);
        while (mask) {
            int srcl = __ffsll(mask) - 1;
            mask &= mask - 1;
            int rr = __shfl(r, srcl, 64);
            int cc = __shfl(c, srcl, 64);
            float vv = __shfl(v, srcl, 64);
            const float* sp = (cc < G_N) ? (ge + (size_t)cc * 64) : (ie + (size_t)(cc - G_N) * 64);
            atomicAdd(&out[(size_t)rr * 64 + lane], vv * sp[lane]);
        }
    }
}

// ---------------- accumulation helpers ----------------

__global__ void k_add_grp(float* __restrict__ dst, const __hip_bfloat16* __restrict__ src, int n) {
    int i = blockIdx.x * 256 + threadIdx.x;
    if (i < n) dst[i] += __bfloat162float(src[i]);
}

__global__ void k_init_user_acc(const int* __restrict__ ui, const float* __restrict__ ue,
                                float* __restrict__ ua) {
    int idx = blockIdx.x * 256 + threadIdx.x;
    if (idx >= B_N * 64) return;
    int b = idx >> 6, d = idx & 63;
    ua[idx] = ue[(size_t)ui[b] * 64 + d];
}

__global__ void k_acc_user(const int* __restrict__ ui, const __hip_bfloat16* __restrict__ cur,
                           float* __restrict__ ua) {
    int idx = blockIdx.x * 256 + threadIdx.x;
    if (idx >= B_N * 64) return;
    int b = idx >> 6, d = idx & 63;
    ua[idx] += __bfloat162float(cur[(size_t)ui[b] * 64 + d]);
}

// concat(user_emb, group_emb) f32 -> bf16 table (vectorized 4/thread)
__global__ void k_cvt_cat(const float4* __restrict__ ue4, const float4* __restrict__ ge4,
                          ushort4* __restrict__ out4) {
    int i = blockIdx.x * 256 + threadIdx.x;
    if (i >= NHG * 16) return;
    float4 f = (i < U_N * 16) ? ue4[i] : ge4[i - U_N * 16];
    ushort4 o;
    o.x = (unsigned short)bfc(f.x);
    o.y = (unsigned short)bfc(f.y);
    o.z = (unsigned short)bfc(f.z);
    o.w = (unsigned short)bfc(f.w);
    out4[i] = o;
}

// ---------------- gg = gg_graph @ group_emb via MFMA bf16 ----------------

// Bfrag[(kc*4 + ct)*64 + lane][e] = bf16(B[kc*32 + (lane>>4)*8 + e][ct*16 + (lane&15)])
__global__ void k_bfrag(const float* __restrict__ B, short* __restrict__ Bfrag) {
    int t = blockIdx.x * 256 + threadIdx.x;  // t < 313*4*64 exactly
    int l = t & 63;
    int ct = (t >> 6) & 3;
    int kc = t >> 8;
    int j = ct * 16 + (l & 15);
    int kb = kc * 32 + (l >> 4) * 8;
    short v[8];
#pragma unroll
    for (int e = 0; e < 8; ++e) {
        int k = kb + e;
        float f = (k < GG_K) ? B[(size_t)k * 64 + j] : 0.f;
        v[e] = bfc(f);
    }
    bf16x8 pack;
#pragma unroll
    for (int e = 0; e < 8; ++e) pack[e] = v[e];
    *(bf16x8*)(Bfrag + (size_t)t * 8) = pack;
}

// 628 blocks = 157 row-stripes x 4 K-splits; 256 thr = 4 waves x 16 rows.
__global__ __launch_bounds__(256) void gg_mfma(const float* __restrict__ A,
                                               const short* __restrict__ Bfrag,
                                               float* __restrict__ part) {
    const int stripe = blockIdx.x % GG_STRIPES;
    const int ks = blockIdx.x / GG_STRIPES;  // 0..3
    const int w = threadIdx.x >> 6;
    const int l = threadIdx.x & 63;
    const int r0w = stripe * 64 + w * 16;
    int arow_i = r0w + (l & 15);
    if (arow_i > GG_K - 1) arow_i = GG_K - 1;  // clamp (dup read, store guarded)
    const float* arow = A + (size_t)arow_i * GG_K;
    const int kg8 = (l >> 4) * 8;
    const int c0 = (ks == 0) ? 0 : 79 + 78 * (ks - 1);
    const int c1 = c0 + ((ks == 0) ? 79 : 78);
    f32x4 acc0 = {0.f, 0.f, 0.f, 0.f}, acc1 = acc0, acc2 = acc0, acc3 = acc0;
    for (int kc = c0; kc < c1; ++kc) {
        const int kbase = kc * 32 + kg8;
        bf16x8 af;
        if (kc != GG_KC - 1) {
            const float4 a0 = *(const float4*)(arow + kbase);
            const float4 a1 = *(const float4*)(arow + kbase + 4);
            af[0] = bfc(a0.x); af[1] = bfc(a0.y); af[2] = bfc(a0.z); af[3] = bfc(a0.w);
            af[4] = bfc(a1.x); af[5] = bfc(a1.y); af[6] = bfc(a1.z); af[7] = bfc(a1.w);
        } else {
#pragma unroll
            for (int e = 0; e < 8; ++e) {
                int k = kbase + e;
                af[e] = bfc((k < GG_K) ? arow[k] : 0.f);
            }
        }
        const bf16x8* bp = (const bf16x8*)(Bfrag + (size_t)kc * 4 * 64 * 8);
        bf16x8 b0 = bp[0 * 64 + l];
        bf16x8 b1 = bp[1 * 64 + l];
        bf16x8 b2 = bp[2 * 64 + l];
        bf16x8 b3 = bp[3 * 64 + l];
        acc0 = __builtin_amdgcn_mfma_f32_16x16x32_bf16(af, b0, acc0, 0, 0, 0);
        acc1 = __builtin_amdgcn_mfma_f32_16x16x32_bf16(af, b1, acc1, 0, 0, 0);
        acc2 = __builtin_amdgcn_mfma_f32_16x16x32_bf16(af, b2, acc2, 0, 0, 0);
        acc3 = __builtin_amdgcn_mfma_f32_16x16x32_bf16(af, b3, acc3, 0, 0, 0);
    }
    // D layout: row = (l>>4)*4 + reg, col = ct*16 + (l&15)
    float* po = part + (size_t)ks * GG_K * 64;
    const int orow0 = r0w + (l >> 4) * 4;
    const int ocol = l & 15;
#pragma unroll
    for (int reg = 0; reg < 4; ++reg) {
        int orow = orow0 + reg;
        if (orow < GG_K) {
            float* q = po + (size_t)orow * 64 + ocol;
            q[0]  = acc0[reg];
            q[16] = acc1[reg];
            q[32] = acc2[reg];
            q[48] = acc3[reg];
        }
    }
}

__global__ void k_gg_reduce(const float* __restrict__ part, float* __restrict__ out) {
    int i = blockIdx.x * 256 + threadIdx.x;  // < 640000
    const size_t S = (size_t)GG_K * 64;
    out[i] = part[i] + part[S + i] + part[2 * S + i] + part[3 * S + i];
}

// ---------------- finalize groups ----------------

__global__ void k_finalize(const float* __restrict__ ga, const float* __restrict__ gi,
                           const float* __restrict__ gg, const float* __restrict__ hw,
                           const float* __restrict__ hb, const float* __restrict__ lw,
                           const float* __restrict__ lb, const float* __restrict__ ow,
                           const float* __restrict__ ob, float* __restrict__ gf) {
    int g = blockIdx.x * 4 + (threadIdx.x >> 6);
    if (g >= G_N) return;
    int lane = threadIdx.x & 63;
    size_t o = (size_t)g * 64 + lane;
    float hgv = ga[o] * 0.25f;  // /(LAYERS+1)
    float giv = gi[o];
    float ggv = gg[o];
    float d1 = hgv * hw[lane], d2 = giv * lw[lane], d3 = ggv * ow[lane];
#pragma unroll
    for (int off = 32; off; off >>= 1) {
        d1 += __shfl_xor(d1, off, 64);
        d2 += __shfl_xor(d2, off, 64);
        d3 += __shfl_xor(d3, off, 64);
    }
    float hc = sigmoidf_(d1 + hb[0]);
    float lc = sigmoidf_(d2 + lb[0]);
    float oc = sigmoidf_(d3 + ob[0]);
    gf[o] = hc * hgv + lc * giv + oc * ggv;
}

// ---------------- gather outputs (f32) ----------------

__global__ void k_gather_out(const int* __restrict__ ui, const int* __restrict__ pg,
                             const int* __restrict__ ng, const float* __restrict__ ua,
                             const float* __restrict__ gf, const float* __restrict__ ue,
                             const float* __restrict__ ge, float* __restrict__ out) {
    int idx = blockIdx.x * 256 + threadIdx.x;
    if (idx >= B_N * 64) return;
    int b = idx >> 6, d = idx & 63;
    const int S = B_N * 64;
    int u = ui[b], p = pg[b], q = ng[b];
    out[idx]         = ua[idx] * 0.25f;
    out[S + idx]     = gf[(size_t)p * 64 + d];
    out[2 * S + idx] = gf[(size_t)q * 64 + d];
    out[3 * S + idx] = ue[(size_t)u * 64 + d];
    out[4 * S + idx] = ge[(size_t)p * 64 + d];
    out[5 * S + idx] = ge[(size_t)q * 64 + d];
}

extern "C" void kernel_launch(void* const* d_in, const int* in_sizes, int n_in,
                              void* d_out, int out_size, void* d_ws, size_t ws_size,
                              hipStream_t stream) {
    const int*   ui        = (const int*)d_in[0];
    const int*   pg        = (const int*)d_in[1];
    const int*   ng        = (const int*)d_in[2];
    const int*   hg_rows   = (const int*)d_in[3];
    const int*   hg_cols   = (const int*)d_in[4];
    const float* hg_vals   = (const float*)d_in[5];
    const int*   gi_rows   = (const int*)d_in[6];
    const int*   gi_cols   = (const int*)d_in[7];
    const float* gi_vals   = (const float*)d_in[8];
    const float* gg_graph  = (const float*)d_in[9];
    const float* user_emb  = (const float*)d_in[10];
    const float* item_emb  = (const float*)d_in[11];
    const float* group_emb = (const float*)d_in[12];
    const float* hyper_w   = (const float*)d_in[13];
    const float* hyper_b   = (const float*)d_in[14];
    const float* lgcn_w    = (const float*)d_in[15];
    const float* lgcn_b    = (const float*)d_in[16];
    const float* ovl_w     = (const float*)d_in[17];
    const float* ovl_b     = (const float*)d_in[18];
    const int E_HG = in_sizes[3];
    const int E_GI = in_sizes[6];

    const int nblkA = (E_HG + ACHUNK - 1) / ACHUNK;       // 245 at spec size
    const int nM = NBUCK * nblkA;                          // ~201k
    const int nbM = (nM + 1023) / 1024;                    // ~197 (<=256)

    // ---- workspace layout (~85 MB) ----
    char* ws = (char*)d_ws;
    size_t off = 0;
    auto alloc = [&](size_t bytes) -> char* {
        char* p = ws + off;
        off += (bytes + 255) & ~(size_t)255;
        return p;
    };
    int*   M       = (int*)alloc((size_t)nM * 4);
    int2*  bpair   = (int2*)alloc((size_t)E_HG * 8);
    int*   bsums   = (int*)alloc(256 * 4);
    __hip_bfloat16* curA = (__hip_bfloat16*)alloc((size_t)NHG * 64 * 2);
    __hip_bfloat16* curB = (__hip_bfloat16*)alloc((size_t)NHG * 64 * 2);
    float* grp_acc = (float*)alloc((size_t)G_N * 64 * 4);
    float* gi_out  = (float*)alloc((size_t)G_N * 64 * 4);
    float* gg_out  = (float*)alloc((size_t)G_N * 64 * 4);
    float* grp_fin = (float*)alloc((size_t)G_N * 64 * 4);
    float* usr_acc = (float*)alloc((size_t)B_N * 64 * 4);
    short* Bfrag   = (short*)alloc((size_t)GG_KC * 4 * 64 * 8 * 2);
    float* gg_part = (float*)alloc((size_t)4 * GG_K * 64 * 4);
    (void)ws_size; (void)n_in; (void)out_size;

    // --- bucket partition of hg edges (atomic-free) ---
    k_bhist<<<nblkA, 256, 0, stream>>>(hg_rows, M, E_HG, nblkA);
    k_scan_partial<<<nbM, 256, 0, stream>>>(M, M, bsums, nM);
    k_scan_sums<<<1, 256, 0, stream>>>(bsums, nbM);
    k_scan_add<<<nbM, 256, 0, stream>>>(M, bsums, nM);
    k_bscatter<<<nblkA, 256, 0, stream>>>(hg_rows, hg_cols, hg_vals, M, bpair, E_HG, nblkA);

    // --- gi spmm: ballot-batched, no compaction ---
    hipMemsetAsync(gi_out, 0, (size_t)G_N * 64 * 4, stream);
    k_gi_spmm<<<2048, 256, 0, stream>>>(gi_rows, gi_cols, gi_vals,
                                        group_emb, item_emb, gi_out, E_GI);

    // --- gg via MFMA ---
    k_bfrag<<<GG_KC, 256, 0, stream>>>(group_emb, Bfrag);
    gg_mfma<<<GG_STRIPES * 4, 256, 0, stream>>>(gg_graph, Bfrag, gg_part);
    k_gg_reduce<<<(G_N * 64) / 256, 256, 0, stream>>>(gg_part, gg_out);

    // --- init accumulators: acc = hg (layer-0 term) ---
    hipMemcpyAsync(grp_acc, group_emb, (size_t)G_N * 64 * 4, hipMemcpyDeviceToDevice, stream);
    k_init_user_acc<<<(B_N * 64 + 255) / 256, 256, 0, stream>>>(ui, user_emb, usr_acc);

    // --- bf16 base table into curB ---
    k_cvt_cat<<<(NHG * 16 + 255) / 256, 256, 0, stream>>>(
        (const float4*)user_emb, (const float4*)group_emb, (ushort4*)curB);

    const int gadd_blk = (G_N * 64 + 255) / 256;
    const int uacc_blk = (B_N * 64 + 255) / 256;

    // layer 1: curB (base emb bf16) -> curA
    k_spmm_lds<<<NBUCK, 512, 0, stream>>>(M, nblkA, bpair, curB, curA, E_HG);
    k_add_grp<<<gadd_blk, 256, 0, stream>>>(grp_acc, curA + (size_t)U_N * 64, G_N * 64);
    k_acc_user<<<uacc_blk, 256, 0, stream>>>(ui, curA, usr_acc);
    // layer 2: curA -> curB
    k_spmm_lds<<<NBUCK, 512, 0, stream>>>(M, nblkA, bpair, curA, curB, E_HG);
    k_add_grp<<<gadd_blk, 256, 0, stream>>>(grp_acc, curB + (size_t)U_N * 64, G_N * 64);
    k_acc_user<<<uacc_blk, 256, 0, stream>>>(ui, curB, usr_acc);
    // layer 3: curB -> curA
    k_spmm_lds<<<NBUCK, 512, 0, stream>>>(M, nblkA, bpair, curB, curA, E_HG);
    k_add_grp<<<gadd_blk, 256, 0, stream>>>(grp_acc, curA + (size_t)U_N * 64, G_N * 64);
    k_acc_user<<<uacc_blk, 256, 0, stream>>>(ui, curA, usr_acc);

    // finalize + gather
    k_finalize<<<(G_N + 3) / 4, 256, 0, stream>>>(grp_acc, gi_out, gg_out, hyper_w, hyper_b,
                                                  lgcn_w, lgcn_b, ovl_w, ovl_b, grp_fin);
    k_gather_out<<<(B_N * 64 + 255) / 256, 256, 0, stream>>>(ui, pg, ng, usr_acc, grp_fin,
                                                             user_emb, group_emb,
                                                             (float*)d_out);
}

// Round 7
// 626.738 us; speedup vs baseline: 6.2772x; 6.2772x over previous
//
#include <hip/hip_runtime.h>
#include <hip/hip_bf16.h>

#define U_N 200000
#define I_N 100000
#define G_N 10000
#define B_N 8192
#define NHG (U_N + G_N)   /* 210000 */
#define GG_K 10000
#define GG_KC 313         /* ceil(10000/32) k-chunks */
#define GG_STRIPES 157    /* ceil(10000/64) row stripes */

#define BUCK_SHIFT 8
#define BUCK_ROWS 256
#define NBUCK 821         /* ceil(NHG/256) */
#define ACHUNK 12288      /* edges per partition block */

typedef __attribute__((ext_vector_type(8))) short bf16x8;
typedef __attribute__((ext_vector_type(4))) float f32x4;

static __device__ __forceinline__ float sigmoidf_(float x) {
    return 1.0f / (1.0f + __expf(-x));
}

// f32 -> bf16 bits, round-to-nearest-even
static __device__ __forceinline__ short bfc(float x) {
    unsigned u = __float_as_uint(x);
    unsigned r = (u + 0x7fffu + ((u >> 16) & 1u)) >> 16;
    return (short)r;
}

// ---------------- generic scan kernels ----------------

__global__ void k_scan_partial(const int* __restrict__ in, int* __restrict__ out,
                               int* __restrict__ bsums, int n) {
    __shared__ int sh[256];
    int tid = threadIdx.x;
    int base = blockIdx.x * 1024 + tid * 4;
    int v0 = (base + 0 < n) ? in[base + 0] : 0;
    int v1 = (base + 1 < n) ? in[base + 1] : 0;
    int v2 = (base + 2 < n) ? in[base + 2] : 0;
    int v3 = (base + 3 < n) ? in[base + 3] : 0;
    int s = v0 + v1 + v2 + v3;
    sh[tid] = s;
    __syncthreads();
    for (int off = 1; off < 256; off <<= 1) {
        int t = (tid >= off) ? sh[tid - off] : 0;
        __syncthreads();
        if (tid >= off) sh[tid] += t;
        __syncthreads();
    }
    int excl = sh[tid] - s;
    if (tid == 255) bsums[blockIdx.x] = sh[255];
    if (base + 0 < n) out[base + 0] = excl; excl += v0;
    if (base + 1 < n) out[base + 1] = excl; excl += v1;
    if (base + 2 < n) out[base + 2] = excl; excl += v2;
    if (base + 3 < n) out[base + 3] = excl;
}

__global__ void k_scan_sums(int* bsums, int nb) {  // nb <= 256, single block
    __shared__ int sh[256];
    int tid = threadIdx.x;
    int v = (tid < nb) ? bsums[tid] : 0;
    sh[tid] = v;
    __syncthreads();
    for (int off = 1; off < 256; off <<= 1) {
        int t = (tid >= off) ? sh[tid - off] : 0;
        __syncthreads();
        if (tid >= off) sh[tid] += t;
        __syncthreads();
    }
    if (tid < nb) bsums[tid] = sh[tid] - v;  // exclusive
}

__global__ void k_scan_add(int* out, const int* __restrict__ bsums, int n) {
    int base = blockIdx.x * 1024 + threadIdx.x * 4;
    int add = bsums[blockIdx.x];
#pragma unroll
    for (int j = 0; j < 4; ++j)
        if (base + j < n) out[base + j] += add;
}

// ---------------- atomic-free bucket partition ----------------
// M[bucket * nblk + blk] = count of edges in (blk-chunk, bucket); scanned in place.

__global__ void k_bhist(const int* __restrict__ rows, int* __restrict__ M,
                        int nE, int nblk) {
    __shared__ int h[NBUCK];
    for (int i = threadIdx.x; i < NBUCK; i += 256) h[i] = 0;
    __syncthreads();
    int base = blockIdx.x * ACHUNK;
    int end = base + ACHUNK; if (end > nE) end = nE;
    for (int e = base + threadIdx.x; e < end; e += 256)
        atomicAdd(&h[rows[e] >> BUCK_SHIFT], 1);
    __syncthreads();
    for (int b = threadIdx.x; b < NBUCK; b += 256)
        M[(size_t)b * nblk + blockIdx.x] = h[b];
}

// pack: (row & 255) << 24 | col  (col < 2^24), val bits in .y
__global__ void k_bscatter(const int* __restrict__ rows, const int* __restrict__ cols,
                           const float* __restrict__ vals, const int* __restrict__ M,
                           int2* __restrict__ bpair, int nE, int nblk) {
    __shared__ int base[NBUCK];
    for (int i = threadIdx.x; i < NBUCK; i += 256)
        base[i] = M[(size_t)i * nblk + blockIdx.x];
    __syncthreads();
    int s = blockIdx.x * ACHUNK;
    int end = s + ACHUNK; if (end > nE) end = nE;
    for (int e = s + threadIdx.x; e < end; e += 256) {
        int r = rows[e];
        int b = r >> BUCK_SHIFT;
        int pos = atomicAdd(&base[b], 1);  // LDS atomic
        bpair[pos] = make_int2(((r & (BUCK_ROWS - 1)) << 24) | cols[e],
                               __float_as_int(vals[e]));
    }
}

// per-bucket exact CSR: LDS 256-row histogram -> scan -> rank; writes (col,val)
// row-sorted into the bucket's contiguous region of ep, plus rp/cnt per row.
__global__ __launch_bounds__(256) void k_bcsr(const int* __restrict__ M, int nblk,
                                              const int2* __restrict__ bpair,
                                              int2* __restrict__ ep,
                                              int* __restrict__ rp, int* __restrict__ cnt,
                                              int nE) {
    __shared__ int hist[256];
    __shared__ int sc[256];
    const int b = blockIdx.x;
    const int tid = threadIdx.x;
    const int s = M[(size_t)b * nblk];
    const int e_ = (b + 1 < NBUCK) ? M[(size_t)(b + 1) * nblk] : nE;
    hist[tid] = 0;
    __syncthreads();
    for (int i = s + tid; i < e_; i += 256)
        atomicAdd(&hist[((unsigned)bpair[i].x) >> 24], 1);
    __syncthreads();
    int v = hist[tid];
    sc[tid] = v;
    __syncthreads();
    for (int off = 1; off < 256; off <<= 1) {
        int t = (tid >= off) ? sc[tid - off] : 0;
        __syncthreads();
        if (tid >= off) sc[tid] += t;
        __syncthreads();
    }
    int excl = sc[tid] - v;
    int gr = (b << BUCK_SHIFT) + tid;
    if (gr < NHG) { rp[gr] = s + excl; cnt[gr] = v; }
    hist[tid] = excl;  // reuse as cursor
    __syncthreads();
    for (int i = s + tid; i < e_; i += 256) {
        int2 p = bpair[i];
        unsigned pk = (unsigned)p.x;
        int pos = atomicAdd(&hist[pk >> 24], 1);
        ep[s + pos] = make_int2((int)(pk & 0xFFFFFFu >> 0) & 0xFFFFFF, p.y);
    }
}

// ---------------- SpMM (row per wave, unroll-4, fused group accumulate) ----------------
__global__ void k_spmm(const int* __restrict__ rp, const int* __restrict__ cnt,
                       const int2* __restrict__ ep,
                       const __hip_bfloat16* __restrict__ x,
                       __hip_bfloat16* __restrict__ out,
                       float* __restrict__ grp_acc, int nrows) {
    int r = blockIdx.x * 4 + (threadIdx.x >> 6);
    if (r >= nrows) return;
    int lane = threadIdx.x & 63;
    int s = rp[r], n = cnt[r];
    float acc = 0.f;
    int i = 0;
    for (; i + 4 <= n; i += 4) {
        int2 e0 = ep[s + i];
        int2 e1 = ep[s + i + 1];
        int2 e2 = ep[s + i + 2];
        int2 e3 = ep[s + i + 3];
        float x0 = __bfloat162float(x[(size_t)e0.x * 64 + lane]);
        float x1 = __bfloat162float(x[(size_t)e1.x * 64 + lane]);
        float x2 = __bfloat162float(x[(size_t)e2.x * 64 + lane]);
        float x3 = __bfloat162float(x[(size_t)e3.x * 64 + lane]);
        acc += __int_as_float(e0.y) * x0;
        acc += __int_as_float(e1.y) * x1;
        acc += __int_as_float(e2.y) * x2;
        acc += __int_as_float(e3.y) * x3;
    }
    for (; i < n; ++i) {
        int2 e0 = ep[s + i];
        acc += __int_as_float(e0.y) * __bfloat162float(x[(size_t)e0.x * 64 + lane]);
    }
    out[(size_t)r * 64 + lane] = __float2bfloat16(acc);
    if (r >= U_N) grp_acc[(size_t)(r - U_N) * 64 + lane] += acc;
}

// layer-3 targeted spmm: tasks 0..G_N-1 -> group row U_N+t (+= grp_acc);
// tasks G_N.. -> user row ui[b] (+= usr_acc[b])
__global__ void k_spmm_final(const int* __restrict__ rp, const int* __restrict__ cnt,
                             const int2* __restrict__ ep,
                             const __hip_bfloat16* __restrict__ x,
                             const int* __restrict__ ui,
                             float* __restrict__ grp_acc, float* __restrict__ usr_acc) {
    int t = blockIdx.x * 4 + (threadIdx.x >> 6);
    if (t >= G_N + B_N) return;
    int lane = threadIdx.x & 63;
    int r = (t < G_N) ? (U_N + t) : ui[t - G_N];
    int s = rp[r], n = cnt[r];
    float acc = 0.f;
    int i = 0;
    for (; i + 4 <= n; i += 4) {
        int2 e0 = ep[s + i];
        int2 e1 = ep[s + i + 1];
        int2 e2 = ep[s + i + 2];
        int2 e3 = ep[s + i + 3];
        float x0 = __bfloat162float(x[(size_t)e0.x * 64 + lane]);
        float x1 = __bfloat162float(x[(size_t)e1.x * 64 + lane]);
        float x2 = __bfloat162float(x[(size_t)e2.x * 64 + lane]);
        float x3 = __bfloat162float(x[(size_t)e3.x * 64 + lane]);
        acc += __int_as_float(e0.y) * x0;
        acc += __int_as_float(e1.y) * x1;
        acc += __int_as_float(e2.y) * x2;
        acc += __int_as_float(e3.y) * x3;
    }
    for (; i < n; ++i) {
        int2 e0 = ep[s + i];
        acc += __int_as_float(e0.y) * __bfloat162float(x[(size_t)e0.x * 64 + lane]);
    }
    if (t < G_N)
        grp_acc[(size_t)t * 64 + lane] += acc;
    else
        usr_acc[(size_t)(t - G_N) * 64 + lane] += acc;
}

// ---------------- gi spmm: ballot-batched edge-parallel atomic ----------------
__global__ void k_gi_spmm(const int* __restrict__ rows, const int* __restrict__ cols,
                          const float* __restrict__ vals, const float* __restrict__ ge,
                          const float* __restrict__ ie, float* __restrict__ out, int nE) {
    int lane = threadIdx.x & 63;
    long wslot = blockIdx.x * 4 + (threadIdx.x >> 6);
    const long nslots = 2048 * 4;
    for (long base = wslot * 64; base < nE; base += nslots * 64) {
        long e = base + lane;
        int r = (e < nE) ? rows[e] : 0x7fffffff;
        bool ok = (r < G_N);
        int c = 0;
        float v = 0.f;
        if (ok) { c = cols[e]; v = vals[e]; }
        unsigned long long mask = __ballot(ok);
        while (mask) {
            int srcl = __ffsll(mask) - 1;
            mask &= mask - 1;
            int rr = __shfl(r, srcl, 64);
            int cc = __shfl(c, srcl, 64);
            float vv = __shfl(v, srcl, 64);
            const float* sp = (cc < G_N) ? (ge + (size_t)cc * 64) : (ie + (size_t)(cc - G_N) * 64);
            atomicAdd(&out[(size_t)rr * 64 + lane], vv * sp[lane]);
        }
    }
}

// ---------------- accumulation helpers ----------------

__global__ void k_init_user_acc(const int* __restrict__ ui, const float* __restrict__ ue,
                                float* __restrict__ ua) {
    int idx = blockIdx.x * 256 + threadIdx.x;
    if (idx >= B_N * 64) return;
    int b = idx >> 6, d = idx & 63;
    ua[idx] = ue[(size_t)ui[b] * 64 + d];
}

__global__ void k_acc_user(const int* __restrict__ ui, const __hip_bfloat16* __restrict__ cur,
                           float* __restrict__ ua) {
    int idx = blockIdx.x * 256 + threadIdx.x;
    if (idx >= B_N * 64) return;
    int b = idx >> 6, d = idx & 63;
    ua[idx] += __bfloat162float(cur[(size_t)ui[b] * 64 + d]);
}

// concat(user_emb, group_emb) f32 -> bf16 table (vectorized 4/thread)
__global__ void k_cvt_cat(const float4* __restrict__ ue4, const float4* __restrict__ ge4,
                          ushort4* __restrict__ out4) {
    int i = blockIdx.x * 256 + threadIdx.x;
    if (i >= NHG * 16) return;
    float4 f = (i < U_N * 16) ? ue4[i] : ge4[i - U_N * 16];
    ushort4 o;
    o.x = (unsigned short)bfc(f.x);
    o.y = (unsigned short)bfc(f.y);
    o.z = (unsigned short)bfc(f.z);
    o.w = (unsigned short)bfc(f.w);
    out4[i] = o;
}

// ---------------- gg = gg_graph @ group_emb via MFMA bf16 ----------------

__global__ void k_bfrag(const float* __restrict__ B, short* __restrict__ Bfrag) {
    int t = blockIdx.x * 256 + threadIdx.x;  // t < 313*4*64 exactly
    int l = t & 63;
    int ct = (t >> 6) & 3;
    int kc = t >> 8;
    int j = ct * 16 + (l & 15);
    int kb = kc * 32 + (l >> 4) * 8;
    short v[8];
#pragma unroll
    for (int e = 0; e < 8; ++e) {
        int k = kb + e;
        float f = (k < GG_K) ? B[(size_t)k * 64 + j] : 0.f;
        v[e] = bfc(f);
    }
    bf16x8 pack;
#pragma unroll
    for (int e = 0; e < 8; ++e) pack[e] = v[e];
    *(bf16x8*)(Bfrag + (size_t)t * 8) = pack;
}

__global__ __launch_bounds__(256) void gg_mfma(const float* __restrict__ A,
                                               const short* __restrict__ Bfrag,
                                               float* __restrict__ part) {
    const int stripe = blockIdx.x % GG_STRIPES;
    const int ks = blockIdx.x / GG_STRIPES;  // 0..3
    const int w = threadIdx.x >> 6;
    const int l = threadIdx.x & 63;
    const int r0w = stripe * 64 + w * 16;
    int arow_i = r0w + (l & 15);
    if (arow_i > GG_K - 1) arow_i = GG_K - 1;  // clamp (dup read, store guarded)
    const float* arow = A + (size_t)arow_i * GG_K;
    const int kg8 = (l >> 4) * 8;
    const int c0 = (ks == 0) ? 0 : 79 + 78 * (ks - 1);
    const int c1 = c0 + ((ks == 0) ? 79 : 78);
    f32x4 acc0 = {0.f, 0.f, 0.f, 0.f}, acc1 = acc0, acc2 = acc0, acc3 = acc0;
    for (int kc = c0; kc < c1; ++kc) {
        const int kbase = kc * 32 + kg8;
        bf16x8 af;
        if (kc != GG_KC - 1) {
            const float4 a0 = *(const float4*)(arow + kbase);
            const float4 a1 = *(const float4*)(arow + kbase + 4);
            af[0] = bfc(a0.x); af[1] = bfc(a0.y); af[2] = bfc(a0.z); af[3] = bfc(a0.w);
            af[4] = bfc(a1.x); af[5] = bfc(a1.y); af[6] = bfc(a1.z); af[7] = bfc(a1.w);
        } else {
#pragma unroll
            for (int e = 0; e < 8; ++e) {
                int k = kbase + e;
                af[e] = bfc((k < GG_K) ? arow[k] : 0.f);
            }
        }
        const bf16x8* bp = (const bf16x8*)(Bfrag + (size_t)kc * 4 * 64 * 8);
        bf16x8 b0 = bp[0 * 64 + l];
        bf16x8 b1 = bp[1 * 64 + l];
        bf16x8 b2 = bp[2 * 64 + l];
        bf16x8 b3 = bp[3 * 64 + l];
        acc0 = __builtin_amdgcn_mfma_f32_16x16x32_bf16(af, b0, acc0, 0, 0, 0);
        acc1 = __builtin_amdgcn_mfma_f32_16x16x32_bf16(af, b1, acc1, 0, 0, 0);
        acc2 = __builtin_amdgcn_mfma_f32_16x16x32_bf16(af, b2, acc2, 0, 0, 0);
        acc3 = __builtin_amdgcn_mfma_f32_16x16x32_bf16(af, b3, acc3, 0, 0, 0);
    }
    float* po = part + (size_t)ks * GG_K * 64;
    const int orow0 = r0w + (l >> 4) * 4;
    const int ocol = l & 15;
#pragma unroll
    for (int reg = 0; reg < 4; ++reg) {
        int orow = orow0 + reg;
        if (orow < GG_K) {
            float* q = po + (size_t)orow * 64 + ocol;
            q[0]  = acc0[reg];
            q[16] = acc1[reg];
            q[32] = acc2[reg];
            q[48] = acc3[reg];
        }
    }
}

__global__ void k_gg_reduce(const float* __restrict__ part, float* __restrict__ out) {
    int i = blockIdx.x * 256 + threadIdx.x;  // < 640000
    const size_t S = (size_t)GG_K * 64;
    out[i] = part[i] + part[S + i] + part[2 * S + i] + part[3 * S + i];
}

// ---------------- finalize groups ----------------

__global__ void k_finalize(const float* __restrict__ ga, const float* __restrict__ gi,
                           const float* __restrict__ gg, const float* __restrict__ hw,
                           const float* __restrict__ hb, const float* __restrict__ lw,
                           const float* __restrict__ lb, const float* __restrict__ ow,
                           const float* __restrict__ ob, float* __restrict__ gf) {
    int g = blockIdx.x * 4 + (threadIdx.x >> 6);
    if (g >= G_N) return;
    int lane = threadIdx.x & 63;
    size_t o = (size_t)g * 64 + lane;
    float hgv = ga[o] * 0.25f;  // /(LAYERS+1)
    float giv = gi[o];
    float ggv = gg[o];
    float d1 = hgv * hw[lane], d2 = giv * lw[lane], d3 = ggv * ow[lane];
#pragma unroll
    for (int off = 32; off; off >>= 1) {
        d1 += __shfl_xor(d1, off, 64);
        d2 += __shfl_xor(d2, off, 64);
        d3 += __shfl_xor(d3, off, 64);
    }
    float hc = sigmoidf_(d1 + hb[0]);
    float lc = sigmoidf_(d2 + lb[0]);
    float oc = sigmoidf_(d3 + ob[0]);
    gf[o] = hc * hgv + lc * giv + oc * ggv;
}

// ---------------- gather outputs (f32) ----------------

__global__ void k_gather_out(const int* __restrict__ ui, const int* __restrict__ pg,
                             const int* __restrict__ ng, const float* __restrict__ ua,
                             const float* __restrict__ gf, const float* __restrict__ ue,
                             const float* __restrict__ ge, float* __restrict__ out) {
    int idx = blockIdx.x * 256 + threadIdx.x;
    if (idx >= B_N * 64) return;
    int b = idx >> 6, d = idx & 63;
    const int S = B_N * 64;
    int u = ui[b], p = pg[b], q = ng[b];
    out[idx]         = ua[idx] * 0.25f;
    out[S + idx]     = gf[(size_t)p * 64 + d];
    out[2 * S + idx] = gf[(size_t)q * 64 + d];
    out[3 * S + idx] = ue[(size_t)u * 64 + d];
    out[4 * S + idx] = ge[(size_t)p * 64 + d];
    out[5 * S + idx] = ge[(size_t)q * 64 + d];
}

extern "C" void kernel_launch(void* const* d_in, const int* in_sizes, int n_in,
                              void* d_out, int out_size, void* d_ws, size_t ws_size,
                              hipStream_t stream) {
    const int*   ui        = (const int*)d_in[0];
    const int*   pg        = (const int*)d_in[1];
    const int*   ng        = (const int*)d_in[2];
    const int*   hg_rows   = (const int*)d_in[3];
    const int*   hg_cols   = (const int*)d_in[4];
    const float* hg_vals   = (const float*)d_in[5];
    const int*   gi_rows   = (const int*)d_in[6];
    const int*   gi_cols   = (const int*)d_in[7];
    const float* gi_vals   = (const float*)d_in[8];
    const float* gg_graph  = (const float*)d_in[9];
    const float* user_emb  = (const float*)d_in[10];
    const float* item_emb  = (const float*)d_in[11];
    const float* group_emb = (const float*)d_in[12];
    const float* hyper_w   = (const float*)d_in[13];
    const float* hyper_b   = (const float*)d_in[14];
    const float* lgcn_w    = (const float*)d_in[15];
    const float* lgcn_b    = (const float*)d_in[16];
    const float* ovl_w     = (const float*)d_in[17];
    const float* ovl_b     = (const float*)d_in[18];
    const int E_HG = in_sizes[3];
    const int E_GI = in_sizes[6];

    const int nblkA = (E_HG + ACHUNK - 1) / ACHUNK;       // 245 at spec size
    const int nM = NBUCK * nblkA;                          // ~201k
    const int nbM = (nM + 1023) / 1024;                    // <=256

    // ---- workspace layout (~125 MB; ws is ~1.6 GB per poison size) ----
    char* ws = (char*)d_ws;
    size_t off = 0;
    auto alloc = [&](size_t bytes) -> char* {
        char* p = ws + off;
        off += (bytes + 255) & ~(size_t)255;
        return p;
    };
    int*   M       = (int*)alloc((size_t)nM * 4);
    int2*  bpair   = (int2*)alloc((size_t)E_HG * 8);
    int2*  ep      = (int2*)alloc((size_t)E_HG * 8);
    int*   rp      = (int*)alloc((size_t)NHG * 4);
    int*   cnt     = (int*)alloc((size_t)NHG * 4);
    int*   bsums   = (int*)alloc(256 * 4);
    __hip_bfloat16* curA = (__hip_bfloat16*)alloc((size_t)NHG * 64 * 2);
    __hip_bfloat16* curB = (__hip_bfloat16*)alloc((size_t)NHG * 64 * 2);
    float* grp_acc = (float*)alloc((size_t)G_N * 64 * 4);
    float* gi_out  = (float*)alloc((size_t)G_N * 64 * 4);
    float* gg_out  = (float*)alloc((size_t)G_N * 64 * 4);
    float* grp_fin = (float*)alloc((size_t)G_N * 64 * 4);
    float* usr_acc = (float*)alloc((size_t)B_N * 64 * 4);
    short* Bfrag   = (short*)alloc((size_t)GG_KC * 4 * 64 * 8 * 2);
    float* gg_part = (float*)alloc((size_t)4 * GG_K * 64 * 4);
    (void)ws_size; (void)n_in; (void)out_size;

    // --- bucket partition + exact CSR (zero global atomics) ---
    k_bhist<<<nblkA, 256, 0, stream>>>(hg_rows, M, E_HG, nblkA);
    k_scan_partial<<<nbM, 256, 0, stream>>>(M, M, bsums, nM);
    k_scan_sums<<<1, 256, 0, stream>>>(bsums, nbM);
    k_scan_add<<<nbM, 256, 0, stream>>>(M, bsums, nM);
    k_bscatter<<<nblkA, 256, 0, stream>>>(hg_rows, hg_cols, hg_vals, M, bpair, E_HG, nblkA);
    k_bcsr<<<NBUCK, 256, 0, stream>>>(M, nblkA, bpair, ep, rp, cnt, E_HG);

    // --- gi spmm: ballot-batched ---
    hipMemsetAsync(gi_out, 0, (size_t)G_N * 64 * 4, stream);
    k_gi_spmm<<<2048, 256, 0, stream>>>(gi_rows, gi_cols, gi_vals,
                                        group_emb, item_emb, gi_out, E_GI);

    // --- gg via MFMA ---
    k_bfrag<<<GG_KC, 256, 0, stream>>>(group_emb, Bfrag);
    gg_mfma<<<GG_STRIPES * 4, 256, 0, stream>>>(gg_graph, Bfrag, gg_part);
    k_gg_reduce<<<(G_N * 64) / 256, 256, 0, stream>>>(gg_part, gg_out);

    // --- init accumulators: acc = hg (layer-0 term) ---
    hipMemcpyAsync(grp_acc, group_emb, (size_t)G_N * 64 * 4, hipMemcpyDeviceToDevice, stream);
    k_init_user_acc<<<(B_N * 64 + 255) / 256, 256, 0, stream>>>(ui, user_emb, usr_acc);

    // --- bf16 base table into curB ---
    k_cvt_cat<<<(NHG * 16 + 255) / 256, 256, 0, stream>>>(
        (const float4*)user_emb, (const float4*)group_emb, (ushort4*)curB);

    const int spmm_blk = (NHG + 3) / 4;
    const int uacc_blk = (B_N * 64 + 255) / 256;

    // layer 1: curB (base emb bf16) -> curA, grp_acc fused
    k_spmm<<<spmm_blk, 256, 0, stream>>>(rp, cnt, ep, curB, curA, grp_acc, NHG);
    k_acc_user<<<uacc_blk, 256, 0, stream>>>(ui, curA, usr_acc);
    // layer 2: curA -> curB, grp_acc fused
    k_spmm<<<spmm_blk, 256, 0, stream>>>(rp, cnt, ep, curA, curB, grp_acc, NHG);
    k_acc_user<<<uacc_blk, 256, 0, stream>>>(ui, curB, usr_acc);
    // layer 3: targeted (group rows + ui rows only)
    k_spmm_final<<<(G_N + B_N + 3) / 4, 256, 0, stream>>>(rp, cnt, ep, curB, ui,
                                                          grp_acc, usr_acc);

    // finalize + gather
    k_finalize<<<(G_N + 3) / 4, 256, 0, stream>>>(grp_acc, gi_out, gg_out, hyper_w, hyper_b,
                                                  lgcn_w, lgcn_b, ovl_w, ovl_b, grp_fin);
    k_gather_out<<<(B_N * 64 + 255) / 256, 256, 0, stream>>>(ui, pg, ng, usr_acc, grp_fin,
                                                             user_emb, group_emb,
                                                             (float*)d_out);
}

// Round 8
// 547.989 us; speedup vs baseline: 7.1793x; 1.1437x over previous
//
#include <hip/hip_runtime.h>
#include <hip/hip_bf16.h>

#define U_N 200000
#define I_N 100000
#define G_N 10000
#define B_N 8192
#define NHG (U_N + G_N)   /* 210000 */
#define GG_K 10000
#define GG_KC 313         /* ceil(10000/32) k-chunks */
#define GG_STRIPES 157    /* ceil(10000/64) row stripes */
#define GG_SPLIT 8

#define BUCK_SHIFT 8
#define BUCK_ROWS 256
#define NBUCK 821         /* ceil(NHG/256) */
#define ACHUNK 12288      /* edges per partition block */

typedef __attribute__((ext_vector_type(8))) short bf16x8;
typedef __attribute__((ext_vector_type(4))) float f32x4;

static __device__ __forceinline__ float sigmoidf_(float x) {
    return 1.0f / (1.0f + __expf(-x));
}

// f32 -> bf16 bits, round-to-nearest-even
static __device__ __forceinline__ short bfc(float x) {
    unsigned u = __float_as_uint(x);
    unsigned r = (u + 0x7fffu + ((u >> 16) & 1u)) >> 16;
    return (short)r;
}

// ---------------- single-pass bucket partition ----------------
// fixed-capacity bucket regions: bucket b owns [b*cap, (b+1)*cap)

__global__ void k_pinit(int* __restrict__ cursor, int cap) {
    int b = blockIdx.x * 256 + threadIdx.x;
    if (b < NBUCK) cursor[b] = b * cap;
}

// pack: (row & 255) << 24 | col  (col < 2^24), val bits in .y
__global__ void k_bscatter(const int* __restrict__ rows, const int* __restrict__ cols,
                           const float* __restrict__ vals, int* __restrict__ cursor,
                           int2* __restrict__ bpair, int nE, int cap) {
    __shared__ int h[NBUCK];
    __shared__ int base[NBUCK];
    for (int i = threadIdx.x; i < NBUCK; i += 256) h[i] = 0;
    __syncthreads();
    int s = blockIdx.x * ACHUNK;
    int end = s + ACHUNK; if (end > nE) end = nE;
    for (int e = s + threadIdx.x; e < end; e += 256)
        atomicAdd(&h[rows[e] >> BUCK_SHIFT], 1);
    __syncthreads();
    for (int i = threadIdx.x; i < NBUCK; i += 256) {
        int c = h[i];
        base[i] = c ? atomicAdd(&cursor[i], c) : 0;  // reserve contiguous run
        h[i] = 0;                                    // reuse as local rank
    }
    __syncthreads();
    for (int e = s + threadIdx.x; e < end; e += 256) {
        int r = rows[e];
        int b = r >> BUCK_SHIFT;
        int pos = base[b] + atomicAdd(&h[b], 1);     // LDS atomic
        if (pos < (b + 1) * cap)                     // overflow guard (never at spec size)
            bpair[pos] = make_int2(((r & (BUCK_ROWS - 1)) << 24) | cols[e],
                                   __float_as_int(vals[e]));
    }
}

// per-bucket exact CSR: LDS 256-row histogram -> scan -> rank; writes (col,val)
// row-sorted into the bucket's region of ep, plus rp/cnt per row.
__global__ __launch_bounds__(256) void k_bcsr(const int* __restrict__ cursor,
                                              const int2* __restrict__ bpair,
                                              int2* __restrict__ ep,
                                              int* __restrict__ rp, int* __restrict__ cnt,
                                              int cap) {
    __shared__ int hist[256];
    __shared__ int sc[256];
    const int b = blockIdx.x;
    const int tid = threadIdx.x;
    const int s = b * cap;
    int e_ = cursor[b];
    if (e_ > s + cap) e_ = s + cap;
    hist[tid] = 0;
    __syncthreads();
    for (int i = s + tid; i < e_; i += 256)
        atomicAdd(&hist[((unsigned)bpair[i].x) >> 24], 1);
    __syncthreads();
    int v = hist[tid];
    sc[tid] = v;
    __syncthreads();
    for (int off = 1; off < 256; off <<= 1) {
        int t = (tid >= off) ? sc[tid - off] : 0;
        __syncthreads();
        if (tid >= off) sc[tid] += t;
        __syncthreads();
    }
    int excl = sc[tid] - v;
    int gr = (b << BUCK_SHIFT) + tid;
    if (gr < NHG) { rp[gr] = s + excl; cnt[gr] = v; }
    hist[tid] = excl;  // reuse as cursor
    __syncthreads();
    for (int i = s + tid; i < e_; i += 256) {
        int2 p = bpair[i];
        unsigned pk = (unsigned)p.x;
        int pos = atomicAdd(&hist[pk >> 24], 1);
        ep[s + pos] = make_int2((int)(pk & 0xFFFFFFu), p.y);
    }
}

// ---------------- SpMM (row per wave, unroll 8/4/2/1, fused group accumulate) ---------

static __device__ __forceinline__ float spmm_row(const int2* __restrict__ ep, int s, int n,
                                                 const __hip_bfloat16* __restrict__ x,
                                                 int lane) {
    float acc = 0.f;
    int i = 0;
    for (; i + 8 <= n; i += 8) {
        int2 e[8]; float xv[8];
#pragma unroll
        for (int j = 0; j < 8; ++j) e[j] = ep[s + i + j];
#pragma unroll
        for (int j = 0; j < 8; ++j) xv[j] = __bfloat162float(x[(size_t)e[j].x * 64 + lane]);
#pragma unroll
        for (int j = 0; j < 8; ++j) acc += __int_as_float(e[j].y) * xv[j];
    }
    if (i + 4 <= n) {
        int2 e[4]; float xv[4];
#pragma unroll
        for (int j = 0; j < 4; ++j) e[j] = ep[s + i + j];
#pragma unroll
        for (int j = 0; j < 4; ++j) xv[j] = __bfloat162float(x[(size_t)e[j].x * 64 + lane]);
#pragma unroll
        for (int j = 0; j < 4; ++j) acc += __int_as_float(e[j].y) * xv[j];
        i += 4;
    }
    if (i + 2 <= n) {
        int2 e0 = ep[s + i], e1 = ep[s + i + 1];
        float x0 = __bfloat162float(x[(size_t)e0.x * 64 + lane]);
        float x1 = __bfloat162float(x[(size_t)e1.x * 64 + lane]);
        acc += __int_as_float(e0.y) * x0 + __int_as_float(e1.y) * x1;
        i += 2;
    }
    if (i < n) {
        int2 e0 = ep[s + i];
        acc += __int_as_float(e0.y) * __bfloat162float(x[(size_t)e0.x * 64 + lane]);
    }
    return acc;
}

__global__ void k_spmm(const int* __restrict__ rp, const int* __restrict__ cnt,
                       const int2* __restrict__ ep,
                       const __hip_bfloat16* __restrict__ x,
                       __hip_bfloat16* __restrict__ out,
                       float* __restrict__ grp_acc, int nrows) {
    int r = blockIdx.x * 4 + (threadIdx.x >> 6);
    if (r >= nrows) return;
    int lane = threadIdx.x & 63;
    float acc = spmm_row(ep, rp[r], cnt[r], x, lane);
    out[(size_t)r * 64 + lane] = __float2bfloat16(acc);
    if (r >= U_N) grp_acc[(size_t)(r - U_N) * 64 + lane] += acc;
}

// layer-3 targeted spmm: tasks 0..G_N-1 -> group row U_N+t (+= grp_acc);
// tasks G_N.. -> user row ui[b] (+= usr_acc[b])
__global__ void k_spmm_final(const int* __restrict__ rp, const int* __restrict__ cnt,
                             const int2* __restrict__ ep,
                             const __hip_bfloat16* __restrict__ x,
                             const int* __restrict__ ui,
                             float* __restrict__ grp_acc, float* __restrict__ usr_acc) {
    int t = blockIdx.x * 4 + (threadIdx.x >> 6);
    if (t >= G_N + B_N) return;
    int lane = threadIdx.x & 63;
    int r = (t < G_N) ? (U_N + t) : ui[t - G_N];
    float acc = spmm_row(ep, rp[r], cnt[r], x, lane);
    if (t < G_N)
        grp_acc[(size_t)t * 64 + lane] += acc;
    else
        usr_acc[(size_t)(t - G_N) * 64 + lane] += acc;
}

// ---------------- gi spmm: ballot-batched edge-parallel atomic ----------------
__global__ void k_gi_spmm(const int* __restrict__ rows, const int* __restrict__ cols,
                          const float* __restrict__ vals, const float* __restrict__ ge,
                          const float* __restrict__ ie, float* __restrict__ out, int nE) {
    int lane = threadIdx.x & 63;
    long wslot = blockIdx.x * 4 + (threadIdx.x >> 6);
    const long nslots = 2048 * 4;
    for (long base = wslot * 64; base < nE; base += nslots * 64) {
        long e = base + lane;
        int r = (e < nE) ? rows[e] : 0x7fffffff;
        bool ok = (r < G_N);
        int c = 0;
        float v = 0.f;
        if (ok) { c = cols[e]; v = vals[e]; }
        unsigned long long mask = __ballot(ok);
        while (mask) {
            int srcl = __ffsll(mask) - 1;
            mask &= mask - 1;
            int rr = __shfl(r, srcl, 64);
            int cc = __shfl(c, srcl, 64);
            float vv = __shfl(v, srcl, 64);
            const float* sp = (cc < G_N) ? (ge + (size_t)cc * 64) : (ie + (size_t)(cc - G_N) * 64);
            atomicAdd(&out[(size_t)rr * 64 + lane], vv * sp[lane]);
        }
    }
}

// ---------------- accumulation helpers ----------------

__global__ void k_init_user_acc(const int* __restrict__ ui, const float* __restrict__ ue,
                                float* __restrict__ ua) {
    int idx = blockIdx.x * 256 + threadIdx.x;
    if (idx >= B_N * 64) return;
    int b = idx >> 6, d = idx & 63;
    ua[idx] = ue[(size_t)ui[b] * 64 + d];
}

__global__ void k_acc_user(const int* __restrict__ ui, const __hip_bfloat16* __restrict__ cur,
                           float* __restrict__ ua) {
    int idx = blockIdx.x * 256 + threadIdx.x;
    if (idx >= B_N * 64) return;
    int b = idx >> 6, d = idx & 63;
    ua[idx] += __bfloat162float(cur[(size_t)ui[b] * 64 + d]);
}

// concat(user_emb, group_emb) f32 -> bf16 table (vectorized 4/thread)
__global__ void k_cvt_cat(const float4* __restrict__ ue4, const float4* __restrict__ ge4,
                          ushort4* __restrict__ out4) {
    int i = blockIdx.x * 256 + threadIdx.x;
    if (i >= NHG * 16) return;
    float4 f = (i < U_N * 16) ? ue4[i] : ge4[i - U_N * 16];
    ushort4 o;
    o.x = (unsigned short)bfc(f.x);
    o.y = (unsigned short)bfc(f.y);
    o.z = (unsigned short)bfc(f.z);
    o.w = (unsigned short)bfc(f.w);
    out4[i] = o;
}

// ---------------- gg = gg_graph @ group_emb via MFMA bf16 ----------------

__global__ void k_bfrag(const float* __restrict__ B, short* __restrict__ Bfrag) {
    int t = blockIdx.x * 256 + threadIdx.x;  // t < 313*4*64 exactly
    int l = t & 63;
    int ct = (t >> 6) & 3;
    int kc = t >> 8;
    int j = ct * 16 + (l & 15);
    int kb = kc * 32 + (l >> 4) * 8;
    short v[8];
#pragma unroll
    for (int e = 0; e < 8; ++e) {
        int k = kb + e;
        float f = (k < GG_K) ? B[(size_t)k * 64 + j] : 0.f;
        v[e] = bfc(f);
    }
    bf16x8 pack;
#pragma unroll
    for (int e = 0; e < 8; ++e) pack[e] = v[e];
    *(bf16x8*)(Bfrag + (size_t)t * 8) = pack;
}

// 1256 blocks = 157 row-stripes x 8 K-splits; 256 thr = 4 waves x 16 rows.
__global__ __launch_bounds__(256) void gg_mfma(const float* __restrict__ A,
                                               const short* __restrict__ Bfrag,
                                               float* __restrict__ part) {
    const int stripe = blockIdx.x % GG_STRIPES;
    const int ks = blockIdx.x / GG_STRIPES;  // 0..7
    const int w = threadIdx.x >> 6;
    const int l = threadIdx.x & 63;
    const int r0w = stripe * 64 + w * 16;
    int arow_i = r0w + (l & 15);
    if (arow_i > GG_K - 1) arow_i = GG_K - 1;  // clamp (dup read, store guarded)
    const float* arow = A + (size_t)arow_i * GG_K;
    const int kg8 = (l >> 4) * 8;
    // 313 = 40 + 7*39
    const int c0 = (ks == 0) ? 0 : 40 + 39 * (ks - 1);
    const int c1 = c0 + ((ks == 0) ? 40 : 39);
    f32x4 acc0 = {0.f, 0.f, 0.f, 0.f}, acc1 = acc0, acc2 = acc0, acc3 = acc0;
    for (int kc = c0; kc < c1; ++kc) {
        const int kbase = kc * 32 + kg8;
        bf16x8 af;
        if (kc != GG_KC - 1) {
            const float4 a0 = *(const float4*)(arow + kbase);
            const float4 a1 = *(const float4*)(arow + kbase + 4);
            af[0] = bfc(a0.x); af[1] = bfc(a0.y); af[2] = bfc(a0.z); af[3] = bfc(a0.w);
            af[4] = bfc(a1.x); af[5] = bfc(a1.y); af[6] = bfc(a1.z); af[7] = bfc(a1.w);
        } else {
#pragma unroll
            for (int e = 0; e < 8; ++e) {
                int k = kbase + e;
                af[e] = bfc((k < GG_K) ? arow[k] : 0.f);
            }
        }
        const bf16x8* bp = (const bf16x8*)(Bfrag + (size_t)kc * 4 * 64 * 8);
        bf16x8 b0 = bp[0 * 64 + l];
        bf16x8 b1 = bp[1 * 64 + l];
        bf16x8 b2 = bp[2 * 64 + l];
        bf16x8 b3 = bp[3 * 64 + l];
        acc0 = __builtin_amdgcn_mfma_f32_16x16x32_bf16(af, b0, acc0, 0, 0, 0);
        acc1 = __builtin_amdgcn_mfma_f32_16x16x32_bf16(af, b1, acc1, 0, 0, 0);
        acc2 = __builtin_amdgcn_mfma_f32_16x16x32_bf16(af, b2, acc2, 0, 0, 0);
        acc3 = __builtin_amdgcn_mfma_f32_16x16x32_bf16(af, b3, acc3, 0, 0, 0);
    }
    float* po = part + (size_t)ks * GG_K * 64;
    const int orow0 = r0w + (l >> 4) * 4;
    const int ocol = l & 15;
#pragma unroll
    for (int reg = 0; reg < 4; ++reg) {
        int orow = orow0 + reg;
        if (orow < GG_K) {
            float* q = po + (size_t)orow * 64 + ocol;
            q[0]  = acc0[reg];
            q[16] = acc1[reg];
            q[32] = acc2[reg];
            q[48] = acc3[reg];
        }
    }
}

__global__ void k_gg_reduce(const float* __restrict__ part, float* __restrict__ out) {
    int i = blockIdx.x * 256 + threadIdx.x;  // < 640000
    const size_t S = (size_t)GG_K * 64;
    float a = 0.f;
#pragma unroll
    for (int p = 0; p < GG_SPLIT; ++p) a += part[p * S + i];
    out[i] = a;
}

// ---------------- finalize groups ----------------

__global__ void k_finalize(const float* __restrict__ ga, const float* __restrict__ gi,
                           const float* __restrict__ gg, const float* __restrict__ hw,
                           const float* __restrict__ hb, const float* __restrict__ lw,
                           const float* __restrict__ lb, const float* __restrict__ ow,
                           const float* __restrict__ ob, float* __restrict__ gf) {
    int g = blockIdx.x * 4 + (threadIdx.x >> 6);
    if (g >= G_N) return;
    int lane = threadIdx.x & 63;
    size_t o = (size_t)g * 64 + lane;
    float hgv = ga[o] * 0.25f;  // /(LAYERS+1)
    float giv = gi[o];
    float ggv = gg[o];
    float d1 = hgv * hw[lane], d2 = giv * lw[lane], d3 = ggv * ow[lane];
#pragma unroll
    for (int off = 32; off; off >>= 1) {
        d1 += __shfl_xor(d1, off, 64);
        d2 += __shfl_xor(d2, off, 64);
        d3 += __shfl_xor(d3, off, 64);
    }
    float hc = sigmoidf_(d1 + hb[0]);
    float lc = sigmoidf_(d2 + lb[0]);
    float oc = sigmoidf_(d3 + ob[0]);
    gf[o] = hc * hgv + lc * giv + oc * ggv;
}

// ---------------- gather outputs (f32) ----------------

__global__ void k_gather_out(const int* __restrict__ ui, const int* __restrict__ pg,
                             const int* __restrict__ ng, const float* __restrict__ ua,
                             const float* __restrict__ gf, const float* __restrict__ ue,
                             const float* __restrict__ ge, float* __restrict__ out) {
    int idx = blockIdx.x * 256 + threadIdx.x;
    if (idx >= B_N * 64) return;
    int b = idx >> 6, d = idx & 63;
    const int S = B_N * 64;
    int u = ui[b], p = pg[b], q = ng[b];
    out[idx]         = ua[idx] * 0.25f;
    out[S + idx]     = gf[(size_t)p * 64 + d];
    out[2 * S + idx] = gf[(size_t)q * 64 + d];
    out[3 * S + idx] = ue[(size_t)u * 64 + d];
    out[4 * S + idx] = ge[(size_t)p * 64 + d];
    out[5 * S + idx] = ge[(size_t)q * 64 + d];
}

extern "C" void kernel_launch(void* const* d_in, const int* in_sizes, int n_in,
                              void* d_out, int out_size, void* d_ws, size_t ws_size,
                              hipStream_t stream) {
    const int*   ui        = (const int*)d_in[0];
    const int*   pg        = (const int*)d_in[1];
    const int*   ng        = (const int*)d_in[2];
    const int*   hg_rows   = (const int*)d_in[3];
    const int*   hg_cols   = (const int*)d_in[4];
    const float* hg_vals   = (const float*)d_in[5];
    const int*   gi_rows   = (const int*)d_in[6];
    const int*   gi_cols   = (const int*)d_in[7];
    const float* gi_vals   = (const float*)d_in[8];
    const float* gg_graph  = (const float*)d_in[9];
    const float* user_emb  = (const float*)d_in[10];
    const float* item_emb  = (const float*)d_in[11];
    const float* group_emb = (const float*)d_in[12];
    const float* hyper_w   = (const float*)d_in[13];
    const float* hyper_b   = (const float*)d_in[14];
    const float* lgcn_w    = (const float*)d_in[15];
    const float* lgcn_b    = (const float*)d_in[16];
    const float* ovl_w     = (const float*)d_in[17];
    const float* ovl_b     = (const float*)d_in[18];
    const int E_HG = in_sizes[3];
    const int E_GI = in_sizes[6];

    const int nblkA = (E_HG + ACHUNK - 1) / ACHUNK;   // 245 at spec size
    // bucket capacity: mean + 25% + pad (spec: mean 3654 -> cap ~4608; sigma=60)
    int cap = (E_HG + NBUCK - 1) / NBUCK;
    cap = cap + cap / 4 + 64;
    cap = (cap + 63) & ~63;

    // ---- workspace layout (~135 MB; ws is ~1.6 GB) ----
    char* ws = (char*)d_ws;
    size_t off = 0;
    auto alloc = [&](size_t bytes) -> char* {
        char* p = ws + off;
        off += (bytes + 255) & ~(size_t)255;
        return p;
    };
    int*   cursor  = (int*)alloc((size_t)NBUCK * 4);
    int2*  bpair   = (int2*)alloc((size_t)NBUCK * cap * 8);
    int2*  ep      = (int2*)alloc((size_t)NBUCK * cap * 8);
    int*   rp      = (int*)alloc((size_t)NHG * 4);
    int*   cnt     = (int*)alloc((size_t)NHG * 4);
    __hip_bfloat16* curA = (__hip_bfloat16*)alloc((size_t)NHG * 64 * 2);
    __hip_bfloat16* curB = (__hip_bfloat16*)alloc((size_t)NHG * 64 * 2);
    float* grp_acc = (float*)alloc((size_t)G_N * 64 * 4);
    float* gi_out  = (float*)alloc((size_t)G_N * 64 * 4);
    float* gg_out  = (float*)alloc((size_t)G_N * 64 * 4);
    float* grp_fin = (float*)alloc((size_t)G_N * 64 * 4);
    float* usr_acc = (float*)alloc((size_t)B_N * 64 * 4);
    short* Bfrag   = (short*)alloc((size_t)GG_KC * 4 * 64 * 8 * 2);
    float* gg_part = (float*)alloc((size_t)GG_SPLIT * GG_K * 64 * 4);
    (void)ws_size; (void)n_in; (void)out_size;

    // --- single-pass bucket partition + per-bucket CSR ---
    k_pinit<<<(NBUCK + 255) / 256, 256, 0, stream>>>(cursor, cap);
    k_bscatter<<<nblkA, 256, 0, stream>>>(hg_rows, hg_cols, hg_vals, cursor, bpair, E_HG, cap);
    k_bcsr<<<NBUCK, 256, 0, stream>>>(cursor, bpair, ep, rp, cnt, cap);

    // --- gi spmm: ballot-batched ---
    hipMemsetAsync(gi_out, 0, (size_t)G_N * 64 * 4, stream);
    k_gi_spmm<<<2048, 256, 0, stream>>>(gi_rows, gi_cols, gi_vals,
                                        group_emb, item_emb, gi_out, E_GI);

    // --- gg via MFMA (K-split 8) ---
    k_bfrag<<<GG_KC, 256, 0, stream>>>(group_emb, Bfrag);
    gg_mfma<<<GG_STRIPES * GG_SPLIT, 256, 0, stream>>>(gg_graph, Bfrag, gg_part);
    k_gg_reduce<<<(G_N * 64) / 256, 256, 0, stream>>>(gg_part, gg_out);

    // --- init accumulators: acc = hg (layer-0 term) ---
    hipMemcpyAsync(grp_acc, group_emb, (size_t)G_N * 64 * 4, hipMemcpyDeviceToDevice, stream);
    k_init_user_acc<<<(B_N * 64 + 255) / 256, 256, 0, stream>>>(ui, user_emb, usr_acc);

    // --- bf16 base table into curB ---
    k_cvt_cat<<<(NHG * 16 + 255) / 256, 256, 0, stream>>>(
        (const float4*)user_emb, (const float4*)group_emb, (ushort4*)curB);

    const int spmm_blk = (NHG + 3) / 4;
    const int uacc_blk = (B_N * 64 + 255) / 256;

    // layer 1: curB (base emb bf16) -> curA, grp_acc fused
    k_spmm<<<spmm_blk, 256, 0, stream>>>(rp, cnt, ep, curB, curA, grp_acc, NHG);
    k_acc_user<<<uacc_blk, 256, 0, stream>>>(ui, curA, usr_acc);
    // layer 2: curA -> curB, grp_acc fused
    k_spmm<<<spmm_blk, 256, 0, stream>>>(rp, cnt, ep, curA, curB, grp_acc, NHG);
    k_acc_user<<<uacc_blk, 256, 0, stream>>>(ui, curB, usr_acc);
    // layer 3: targeted (group rows + ui rows only)
    k_spmm_final<<<(G_N + B_N + 3) / 4, 256, 0, stream>>>(rp, cnt, ep, curB, ui,
                                                          grp_acc, usr_acc);

    // finalize + gather
    k_finalize<<<(G_N + 3) / 4, 256, 0, stream>>>(grp_acc, gi_out, gg_out, hyper_w, hyper_b,
                                                  lgcn_w, lgcn_b, ovl_w, ovl_b, grp_fin);
    k_gather_out<<<(B_N * 64 + 255) / 256, 256, 0, stream>>>(ui, pg, ng, usr_acc, grp_fin,
                                                             user_emb, group_emb,
                                                             (float*)d_out);
}

// Round 9
// 507.763 us; speedup vs baseline: 7.7480x; 1.0792x over previous
//
#include <hip/hip_runtime.h>
#include <hip/hip_bf16.h>

#define U_N 200000
#define I_N 100000
#define G_N 10000
#define B_N 8192
#define NHG (U_N + G_N)   /* 210000 */
#define GG_K 10000
#define GG_KC 313         /* ceil(10000/32) k-chunks */
#define GG_STRIPES 157    /* ceil(10000/64) row stripes */
#define GG_SPLIT 8

#define BUCK_SHIFT 8
#define BUCK_ROWS 256
#define NBUCK 821         /* ceil(NHG/256) */
#define ACHUNK 12288      /* edges per partition block */

typedef __attribute__((ext_vector_type(8))) short bf16x8;
typedef __attribute__((ext_vector_type(4))) float f32x4;

static __device__ __forceinline__ float sigmoidf_(float x) {
    return 1.0f / (1.0f + __expf(-x));
}

// f32 -> bf16 bits, round-to-nearest-even
static __device__ __forceinline__ unsigned bfc(float x) {
    unsigned u = __float_as_uint(x);
    return (u + 0x7fffu + ((u >> 16) & 1u)) >> 16;
}
// low/high bf16 of a u32 -> f32
static __device__ __forceinline__ float blo(unsigned u) { return __uint_as_float(u << 16); }
static __device__ __forceinline__ float bhi(unsigned u) { return __uint_as_float(u & 0xffff0000u); }

// ---------------- single-pass bucket partition ----------------

__global__ void k_pinit(int* __restrict__ cursor, int cap) {
    int b = blockIdx.x * 256 + threadIdx.x;
    if (b < NBUCK) cursor[b] = b * cap;
}

// pack: (row & 255) << 24 | col  (col < 2^24), val bits in .y
__global__ void k_bscatter(const int* __restrict__ rows, const int* __restrict__ cols,
                           const float* __restrict__ vals, int* __restrict__ cursor,
                           int2* __restrict__ bpair, int nE, int cap) {
    __shared__ int h[NBUCK];
    __shared__ int base[NBUCK];
    for (int i = threadIdx.x; i < NBUCK; i += 256) h[i] = 0;
    __syncthreads();
    int s = blockIdx.x * ACHUNK;
    int end = s + ACHUNK; if (end > nE) end = nE;
    for (int e = s + threadIdx.x; e < end; e += 256)
        atomicAdd(&h[rows[e] >> BUCK_SHIFT], 1);
    __syncthreads();
    for (int i = threadIdx.x; i < NBUCK; i += 256) {
        int c = h[i];
        base[i] = c ? atomicAdd(&cursor[i], c) : 0;
        h[i] = 0;
    }
    __syncthreads();
    for (int e = s + threadIdx.x; e < end; e += 256) {
        int r = rows[e];
        int b = r >> BUCK_SHIFT;
        int pos = base[b] + atomicAdd(&h[b], 1);
        if (pos < (b + 1) * cap)
            bpair[pos] = make_int2(((r & (BUCK_ROWS - 1)) << 24) | cols[e],
                                   __float_as_int(vals[e]));
    }
}

// per-bucket exact CSR
__global__ __launch_bounds__(256) void k_bcsr(const int* __restrict__ cursor,
                                              const int2* __restrict__ bpair,
                                              int2* __restrict__ ep,
                                              int* __restrict__ rp, int* __restrict__ cnt,
                                              int cap) {
    __shared__ int hist[256];
    __shared__ int sc[256];
    const int b = blockIdx.x;
    const int tid = threadIdx.x;
    const int s = b * cap;
    int e_ = cursor[b];
    if (e_ > s + cap) e_ = s + cap;
    hist[tid] = 0;
    __syncthreads();
    for (int i = s + tid; i < e_; i += 256)
        atomicAdd(&hist[((unsigned)bpair[i].x) >> 24], 1);
    __syncthreads();
    int v = hist[tid];
    sc[tid] = v;
    __syncthreads();
    for (int off = 1; off < 256; off <<= 1) {
        int t = (tid >= off) ? sc[tid - off] : 0;
        __syncthreads();
        if (tid >= off) sc[tid] += t;
        __syncthreads();
    }
    int excl = sc[tid] - v;
    int gr = (b << BUCK_SHIFT) + tid;
    if (gr < NHG) { rp[gr] = s + excl; cnt[gr] = v; }
    hist[tid] = excl;
    __syncthreads();
    for (int i = s + tid; i < e_; i += 256) {
        int2 p = bpair[i];
        unsigned pk = (unsigned)p.x;
        int pos = atomicAdd(&hist[pk >> 24], 1);
        ep[s + pos] = make_int2((int)(pk & 0xFFFFFFu), p.y);
    }
}

// ---------------- SpMM: 2 rows per wave, 32 lanes x u32 (2 bf16 dims) ----------------
// fully predicated unroll-8; returns acc for dims (2*sub, 2*sub+1) of row.

static __device__ __forceinline__ void spmm_row2(const int2* __restrict__ ep, int s, int n,
                                                 int nmax, const unsigned* __restrict__ x32,
                                                 int sub, float& ax, float& ay) {
    ax = 0.f; ay = 0.f;
    for (int i = 0; i < nmax; i += 8) {
        int2 e[8];
#pragma unroll
        for (int j = 0; j < 8; ++j) {
            int k = i + j;
            int kk = (k < n) ? k : (n > 0 ? n - 1 : 0);
            e[j] = ep[s + kk];
            if (k >= n) e[j].y = 0;  // zero weight for padded edges
        }
        unsigned xv[8];
#pragma unroll
        for (int j = 0; j < 8; ++j)
            xv[j] = x32[(size_t)e[j].x * 32 + sub];
#pragma unroll
        for (int j = 0; j < 8; ++j) {
            float v = __int_as_float(e[j].y);
            ax += v * blo(xv[j]);
            ay += v * bhi(xv[j]);
        }
    }
}

// layers 1/2: rows [0,NHG); fused grp_acc for rows >= U_N; optional user-acc grid ext
__global__ void k_spmm2(const int* __restrict__ rp, const int* __restrict__ cnt,
                        const int2* __restrict__ ep, const unsigned* __restrict__ x32,
                        unsigned* __restrict__ out32, float* __restrict__ grp_acc,
                        const int* __restrict__ ui, float* __restrict__ usr_acc,
                        int spmmBlocks) {
    if (blockIdx.x >= spmmBlocks) {
        // user accumulate: ua += x[ui[b]]  (x is this layer's INPUT = prev layer's output)
        int idx = (blockIdx.x - spmmBlocks) * 256 + threadIdx.x;  // < B_N*32
        int b = idx >> 5, d = idx & 31;
        unsigned u = x32[(size_t)ui[b] * 32 + d];
        float2* g = (float2*)usr_acc + ((size_t)b * 32 + d);
        float2 t = *g;
        t.x += blo(u); t.y += bhi(u);
        *g = t;
        return;
    }
    int wid = threadIdx.x >> 6;
    int lane = threadIdx.x & 63;
    int half = lane >> 5, sub = lane & 31;
    int r = blockIdx.x * 8 + wid * 2 + half;
    bool active = (r < NHG);
    int rr = active ? r : NHG - 1;
    int s = rp[rr];
    int n = active ? cnt[rr] : 0;
    int nmax = n;
    nmax = max(nmax, __shfl_xor(nmax, 32, 64));  // max over both halves
    float ax, ay;
    spmm_row2(ep, s, n, nmax, x32, sub, ax, ay);
    if (active) {
        out32[(size_t)r * 32 + sub] = bfc(ax) | (bfc(ay) << 16);
        if (r >= U_N) {
            float2* g = (float2*)grp_acc + ((size_t)(r - U_N) * 32 + sub);
            float2 t = *g;
            t.x += ax; t.y += ay;
            *g = t;
        }
    }
}

// layer 3 targeted: tasks 0..G_N-1 -> group row U_N+t (grp_acc +=);
// tasks G_N..G_N+B_N-1 -> user row ui[b] (usr_acc +=); grid ext: ua += x[ui[b]]
__global__ void k_spmm_final(const int* __restrict__ rp, const int* __restrict__ cnt,
                             const int2* __restrict__ ep, const unsigned* __restrict__ x32,
                             const int* __restrict__ ui,
                             float* __restrict__ grp_acc, float* __restrict__ usr_acc,
                             int taskBlocks) {
    if (blockIdx.x >= taskBlocks) {
        int idx = (blockIdx.x - taskBlocks) * 256 + threadIdx.x;  // < B_N*32
        int b = idx >> 5, d = idx & 31;
        unsigned u = x32[(size_t)ui[b] * 32 + d];
        float2* g = (float2*)usr_acc + ((size_t)b * 32 + d);
        float2 t = *g;
        t.x += blo(u); t.y += bhi(u);
        *g = t;
        return;
    }
    int wid = threadIdx.x >> 6;
    int lane = threadIdx.x & 63;
    int half = lane >> 5, sub = lane & 31;
    int t = blockIdx.x * 8 + wid * 2 + half;
    bool active = (t < G_N + B_N);
    int tt = active ? t : 0;
    int r = (tt < G_N) ? (U_N + tt) : ui[tt - G_N];
    int s = rp[r];
    int n = active ? cnt[r] : 0;
    int nmax = n;
    nmax = max(nmax, __shfl_xor(nmax, 32, 64));
    float ax, ay;
    spmm_row2(ep, s, n, nmax, x32, sub, ax, ay);
    if (active) {
        float2* g = (tt < G_N) ? ((float2*)grp_acc + ((size_t)tt * 32 + sub))
                               : ((float2*)usr_acc + ((size_t)(tt - G_N) * 32 + sub));
        float2 v = *g;
        v.x += ax; v.y += ay;
        *g = v;
    }
}

// ---------------- gi spmm: ballot-batched edge-parallel atomic ----------------
__global__ void k_gi_spmm(const int* __restrict__ rows, const int* __restrict__ cols,
                          const float* __restrict__ vals, const float* __restrict__ ge,
                          const float* __restrict__ ie, float* __restrict__ out, int nE) {
    int lane = threadIdx.x & 63;
    long wslot = blockIdx.x * 4 + (threadIdx.x >> 6);
    const long nslots = 2048 * 4;
    for (long base = wslot * 64; base < nE; base += nslots * 64) {
        long e = base + lane;
        int r = (e < nE) ? rows[e] : 0x7fffffff;
        bool ok = (r < G_N);
        int c = 0;
        float v = 0.f;
        if (ok) { c = cols[e]; v = vals[e]; }
        unsigned long long mask = __ballot(ok);
        while (mask) {
            int srcl = __ffsll(mask) - 1;
            mask &= mask - 1;
            int rr = __shfl(r, srcl, 64);
            int cc = __shfl(c, srcl, 64);
            float vv = __shfl(v, srcl, 64);
            const float* sp = (cc < G_N) ? (ge + (size_t)cc * 64) : (ie + (size_t)(cc - G_N) * 64);
            atomicAdd(&out[(size_t)rr * 64 + lane], vv * sp[lane]);
        }
    }
}

// ---------------- cvt concat + init user acc (fused) ----------------
// blocks [0, cvtBlocks): bf16 table; blocks beyond: usr_acc init from user_emb
__global__ void k_cvt_cat(const float4* __restrict__ ue4, const float4* __restrict__ ge4,
                          ushort4* __restrict__ out4, const int* __restrict__ ui,
                          float* __restrict__ ua, int cvtBlocks) {
    if (blockIdx.x >= cvtBlocks) {
        int idx = (blockIdx.x - cvtBlocks) * 256 + threadIdx.x;  // < B_N*64
        int b = idx >> 6, d = idx & 63;
        ua[idx] = ((const float*)ue4)[(size_t)ui[b] * 64 + d];
        return;
    }
    int i = blockIdx.x * 256 + threadIdx.x;
    if (i >= NHG * 16) return;
    float4 f = (i < U_N * 16) ? ue4[i] : ge4[i - U_N * 16];
    ushort4 o;
    o.x = (unsigned short)bfc(f.x);
    o.y = (unsigned short)bfc(f.y);
    o.z = (unsigned short)bfc(f.z);
    o.w = (unsigned short)bfc(f.w);
    out4[i] = o;
}

// ---------------- gg = gg_graph @ group_emb via MFMA bf16 ----------------

__global__ void k_bfrag(const float* __restrict__ B, short* __restrict__ Bfrag) {
    int t = blockIdx.x * 256 + threadIdx.x;  // t < 313*4*64 exactly
    int l = t & 63;
    int ct = (t >> 6) & 3;
    int kc = t >> 8;
    int j = ct * 16 + (l & 15);
    int kb = kc * 32 + (l >> 4) * 8;
    short v[8];
#pragma unroll
    for (int e = 0; e < 8; ++e) {
        int k = kb + e;
        float f = (k < GG_K) ? B[(size_t)k * 64 + j] : 0.f;
        v[e] = (short)bfc(f);
    }
    bf16x8 pack;
#pragma unroll
    for (int e = 0; e < 8; ++e) pack[e] = v[e];
    *(bf16x8*)(Bfrag + (size_t)t * 8) = pack;
}

// 1256 blocks = 157 row-stripes x 8 K-splits; 256 thr = 4 waves x 16 rows.
__global__ __launch_bounds__(256) void gg_mfma(const float* __restrict__ A,
                                               const short* __restrict__ Bfrag,
                                               float* __restrict__ part) {
    const int stripe = blockIdx.x % GG_STRIPES;
    const int ks = blockIdx.x / GG_STRIPES;  // 0..7
    const int w = threadIdx.x >> 6;
    const int l = threadIdx.x & 63;
    const int r0w = stripe * 64 + w * 16;
    int arow_i = r0w + (l & 15);
    if (arow_i > GG_K - 1) arow_i = GG_K - 1;
    const float* arow = A + (size_t)arow_i * GG_K;
    const int kg8 = (l >> 4) * 8;
    const int c0 = (ks == 0) ? 0 : 40 + 39 * (ks - 1);
    const int c1 = c0 + ((ks == 0) ? 40 : 39);
    f32x4 acc0 = {0.f, 0.f, 0.f, 0.f}, acc1 = acc0, acc2 = acc0, acc3 = acc0;
    for (int kc = c0; kc < c1; ++kc) {
        const int kbase = kc * 32 + kg8;
        bf16x8 af;
        if (kc != GG_KC - 1) {
            const float4 a0 = *(const float4*)(arow + kbase);
            const float4 a1 = *(const float4*)(arow + kbase + 4);
            af[0] = (short)bfc(a0.x); af[1] = (short)bfc(a0.y);
            af[2] = (short)bfc(a0.z); af[3] = (short)bfc(a0.w);
            af[4] = (short)bfc(a1.x); af[5] = (short)bfc(a1.y);
            af[6] = (short)bfc(a1.z); af[7] = (short)bfc(a1.w);
        } else {
#pragma unroll
            for (int e = 0; e < 8; ++e) {
                int k = kbase + e;
                af[e] = (short)bfc((k < GG_K) ? arow[k] : 0.f);
            }
        }
        const bf16x8* bp = (const bf16x8*)(Bfrag + (size_t)kc * 4 * 64 * 8);
        bf16x8 b0 = bp[0 * 64 + l];
        bf16x8 b1 = bp[1 * 64 + l];
        bf16x8 b2 = bp[2 * 64 + l];
        bf16x8 b3 = bp[3 * 64 + l];
        acc0 = __builtin_amdgcn_mfma_f32_16x16x32_bf16(af, b0, acc0, 0, 0, 0);
        acc1 = __builtin_amdgcn_mfma_f32_16x16x32_bf16(af, b1, acc1, 0, 0, 0);
        acc2 = __builtin_amdgcn_mfma_f32_16x16x32_bf16(af, b2, acc2, 0, 0, 0);
        acc3 = __builtin_amdgcn_mfma_f32_16x16x32_bf16(af, b3, acc3, 0, 0, 0);
    }
    float* po = part + (size_t)ks * GG_K * 64;
    const int orow0 = r0w + (l >> 4) * 4;
    const int ocol = l & 15;
#pragma unroll
    for (int reg = 0; reg < 4; ++reg) {
        int orow = orow0 + reg;
        if (orow < GG_K) {
            float* q = po + (size_t)orow * 64 + ocol;
            q[0]  = acc0[reg];
            q[16] = acc1[reg];
            q[32] = acc2[reg];
            q[48] = acc3[reg];
        }
    }
}

// ---------------- finalize groups (with inline 8-way gg reduce) ----------------

__global__ void k_finalize(const float* __restrict__ ga, const float* __restrict__ gi,
                           const float* __restrict__ gg_part, const float* __restrict__ hw,
                           const float* __restrict__ hb, const float* __restrict__ lw,
                           const float* __restrict__ lb, const float* __restrict__ ow,
                           const float* __restrict__ ob, float* __restrict__ gf) {
    int g = blockIdx.x * 4 + (threadIdx.x >> 6);
    if (g >= G_N) return;
    int lane = threadIdx.x & 63;
    size_t o = (size_t)g * 64 + lane;
    float hgv = ga[o] * 0.25f;  // /(LAYERS+1)
    float giv = gi[o];
    const size_t S = (size_t)GG_K * 64;
    float ggv = 0.f;
#pragma unroll
    for (int p = 0; p < GG_SPLIT; ++p) ggv += gg_part[p * S + o];
    float d1 = hgv * hw[lane], d2 = giv * lw[lane], d3 = ggv * ow[lane];
#pragma unroll
    for (int off = 32; off; off >>= 1) {
        d1 += __shfl_xor(d1, off, 64);
        d2 += __shfl_xor(d2, off, 64);
        d3 += __shfl_xor(d3, off, 64);
    }
    float hc = sigmoidf_(d1 + hb[0]);
    float lc = sigmoidf_(d2 + lb[0]);
    float oc = sigmoidf_(d3 + ob[0]);
    gf[o] = hc * hgv + lc * giv + oc * ggv;
}

// ---------------- gather outputs (f32) ----------------

__global__ void k_gather_out(const int* __restrict__ ui, const int* __restrict__ pg,
                             const int* __restrict__ ng, const float* __restrict__ ua,
                             const float* __restrict__ gf, const float* __restrict__ ue,
                             const float* __restrict__ ge, float* __restrict__ out) {
    int idx = blockIdx.x * 256 + threadIdx.x;
    if (idx >= B_N * 64) return;
    int b = idx >> 6, d = idx & 63;
    const int S = B_N * 64;
    int u = ui[b], p = pg[b], q = ng[b];
    out[idx]         = ua[idx] * 0.25f;
    out[S + idx]     = gf[(size_t)p * 64 + d];
    out[2 * S + idx] = gf[(size_t)q * 64 + d];
    out[3 * S + idx] = ue[(size_t)u * 64 + d];
    out[4 * S + idx] = ge[(size_t)p * 64 + d];
    out[5 * S + idx] = ge[(size_t)q * 64 + d];
}

extern "C" void kernel_launch(void* const* d_in, const int* in_sizes, int n_in,
                              void* d_out, int out_size, void* d_ws, size_t ws_size,
                              hipStream_t stream) {
    const int*   ui        = (const int*)d_in[0];
    const int*   pg        = (const int*)d_in[1];
    const int*   ng        = (const int*)d_in[2];
    const int*   hg_rows   = (const int*)d_in[3];
    const int*   hg_cols   = (const int*)d_in[4];
    const float* hg_vals   = (const float*)d_in[5];
    const int*   gi_rows   = (const int*)d_in[6];
    const int*   gi_cols   = (const int*)d_in[7];
    const float* gi_vals   = (const float*)d_in[8];
    const float* gg_graph  = (const float*)d_in[9];
    const float* user_emb  = (const float*)d_in[10];
    const float* item_emb  = (const float*)d_in[11];
    const float* group_emb = (const float*)d_in[12];
    const float* hyper_w   = (const float*)d_in[13];
    const float* hyper_b   = (const float*)d_in[14];
    const float* lgcn_w    = (const float*)d_in[15];
    const float* lgcn_b    = (const float*)d_in[16];
    const float* ovl_w     = (const float*)d_in[17];
    const float* ovl_b     = (const float*)d_in[18];
    const int E_HG = in_sizes[3];
    const int E_GI = in_sizes[6];

    const int nblkA = (E_HG + ACHUNK - 1) / ACHUNK;
    int cap = (E_HG + NBUCK - 1) / NBUCK;
    cap = cap + cap / 4 + 64;
    cap = (cap + 63) & ~63;

    // ---- workspace layout (~135 MB; ws is ~1.6 GB) ----
    char* ws = (char*)d_ws;
    size_t off = 0;
    auto alloc = [&](size_t bytes) -> char* {
        char* p = ws + off;
        off += (bytes + 255) & ~(size_t)255;
        return p;
    };
    int*   cursor  = (int*)alloc((size_t)NBUCK * 4);
    int2*  bpair   = (int2*)alloc((size_t)NBUCK * cap * 8);
    int2*  ep      = (int2*)alloc((size_t)NBUCK * cap * 8 + 1024);  // +pad for clamped reads
    int*   rp      = (int*)alloc((size_t)NHG * 4);
    int*   cnt     = (int*)alloc((size_t)NHG * 4);
    __hip_bfloat16* curA = (__hip_bfloat16*)alloc((size_t)NHG * 64 * 2);
    __hip_bfloat16* curB = (__hip_bfloat16*)alloc((size_t)NHG * 64 * 2);
    float* grp_acc = (float*)alloc((size_t)G_N * 64 * 4);
    float* gi_out  = (float*)alloc((size_t)G_N * 64 * 4);
    float* grp_fin = (float*)alloc((size_t)G_N * 64 * 4);
    float* usr_acc = (float*)alloc((size_t)B_N * 64 * 4);
    short* Bfrag   = (short*)alloc((size_t)GG_KC * 4 * 64 * 8 * 2);
    float* gg_part = (float*)alloc((size_t)GG_SPLIT * GG_K * 64 * 4);
    (void)ws_size; (void)n_in; (void)out_size;

    // --- single-pass bucket partition + per-bucket CSR ---
    k_pinit<<<(NBUCK + 255) / 256, 256, 0, stream>>>(cursor, cap);
    k_bscatter<<<nblkA, 256, 0, stream>>>(hg_rows, hg_cols, hg_vals, cursor, bpair, E_HG, cap);
    k_bcsr<<<NBUCK, 256, 0, stream>>>(cursor, bpair, ep, rp, cnt, cap);

    // --- gi spmm: ballot-batched ---
    hipMemsetAsync(gi_out, 0, (size_t)G_N * 64 * 4, stream);
    k_gi_spmm<<<2048, 256, 0, stream>>>(gi_rows, gi_cols, gi_vals,
                                        group_emb, item_emb, gi_out, E_GI);

    // --- gg via MFMA (K-split 8; reduce folded into finalize) ---
    k_bfrag<<<GG_KC, 256, 0, stream>>>(group_emb, Bfrag);
    gg_mfma<<<GG_STRIPES * GG_SPLIT, 256, 0, stream>>>(gg_graph, Bfrag, gg_part);

    // --- grp_acc init (layer-0 term) ---
    hipMemcpyAsync(grp_acc, group_emb, (size_t)G_N * 64 * 4, hipMemcpyDeviceToDevice, stream);

    // --- bf16 base table into curB + usr_acc init (fused) ---
    const int cvtBlocks = (NHG * 16 + 255) / 256;
    k_cvt_cat<<<cvtBlocks + (B_N * 64) / 256, 256, 0, stream>>>(
        (const float4*)user_emb, (const float4*)group_emb, (ushort4*)curB, ui, usr_acc,
        cvtBlocks);

    const int spmmB = (NHG + 7) / 8;
    const int uaExt = (B_N * 32) / 256;  // 1024 blocks

    // layer 1: curB -> curA (grp_acc fused; no user ext — curA not ready before)
    k_spmm2<<<spmmB, 256, 0, stream>>>(rp, cnt, ep, (const unsigned*)curB,
                                       (unsigned*)curA, grp_acc, nullptr, nullptr, spmmB);
    // layer 2: curA -> curB (grp_acc fused; ext: usr_acc += curA[ui])
    k_spmm2<<<spmmB + uaExt, 256, 0, stream>>>(rp, cnt, ep, (const unsigned*)curA,
                                               (unsigned*)curB, grp_acc, ui, usr_acc, spmmB);
    // layer 3: targeted; ext: usr_acc += curB[ui]
    const int taskB = (G_N + B_N + 7) / 8;
    k_spmm_final<<<taskB + uaExt, 256, 0, stream>>>(rp, cnt, ep, (const unsigned*)curB, ui,
                                                    grp_acc, usr_acc, taskB);

    // finalize (+gg reduce) + gather
    k_finalize<<<(G_N + 3) / 4, 256, 0, stream>>>(grp_acc, gi_out, gg_part, hyper_w, hyper_b,
                                                  lgcn_w, lgcn_b, ovl_w, ovl_b, grp_fin);
    k_gather_out<<<(B_N * 64 + 255) / 256, 256, 0, stream>>>(ui, pg, ng, usr_acc, grp_fin,
                                                             user_emb, group_emb,
                                                             (float*)d_out);
}

// Round 10
// 471.977 us; speedup vs baseline: 8.3355x; 1.0758x over previous
//
#include <hip/hip_runtime.h>
#include <hip/hip_bf16.h>

#define U_N 200000
#define I_N 100000
#define G_N 10000
#define B_N 8192
#define NHG (U_N + G_N)   /* 210000 */
#define GG_K 10000
#define GG_KC 313         /* ceil(10000/32) k-chunks */
#define GG_STRIPES 157    /* ceil(10000/64) row stripes */
#define GG_SPLIT 8

#define BUCK_SHIFT 8
#define BUCK_ROWS 256
#define NBUCK 821         /* ceil(NHG/256) */
#define ACHUNK 12288      /* edges per partition block */

typedef __attribute__((ext_vector_type(8))) short bf16x8;
typedef __attribute__((ext_vector_type(4))) float f32x4;

static __device__ __forceinline__ float sigmoidf_(float x) {
    return 1.0f / (1.0f + __expf(-x));
}

// f32 -> bf16 bits, round-to-nearest-even
static __device__ __forceinline__ unsigned bfc(float x) {
    unsigned u = __float_as_uint(x);
    return (u + 0x7fffu + ((u >> 16) & 1u)) >> 16;
}
static __device__ __forceinline__ float blo(unsigned u) { return __uint_as_float(u << 16); }
static __device__ __forceinline__ float bhi(unsigned u) { return __uint_as_float(u & 0xffff0000u); }

// ================= PHASE 1: all independent prep, one kernel =================
// block ranges: [0,cvtB) cvt | [.,+uaB) ua init | [.,+gaB) grp_acc init
//             | [.,+gzB) gi zero | [.,+bfB) bfrag | [.,+4) cursor init
__global__ void k_phase1(const float4* __restrict__ ue4, const float4* __restrict__ ge4,
                         ushort4* __restrict__ out4, const int* __restrict__ ui,
                         float* __restrict__ ua, float* __restrict__ grp_acc,
                         float* __restrict__ gi_out, short* __restrict__ Bfrag,
                         int* __restrict__ cursor, int cap,
                         int cvtB, int uaB, int gaB, int gzB, int bfB) {
    int bx = blockIdx.x;
    if (bx < cvtB) {
        int i = bx * 256 + threadIdx.x;  // < NHG*16 exactly
        float4 f = (i < U_N * 16) ? ue4[i] : ge4[i - U_N * 16];
        ushort4 o;
        o.x = (unsigned short)bfc(f.x);
        o.y = (unsigned short)bfc(f.y);
        o.z = (unsigned short)bfc(f.z);
        o.w = (unsigned short)bfc(f.w);
        out4[i] = o;
        return;
    }
    bx -= cvtB;
    if (bx < uaB) {
        int idx = bx * 256 + threadIdx.x;  // < B_N*64
        int b = idx >> 6, d = idx & 63;
        ua[idx] = ((const float*)ue4)[(size_t)ui[b] * 64 + d];
        return;
    }
    bx -= uaB;
    if (bx < gaB) {
        int idx = bx * 256 + threadIdx.x;  // < G_N*64
        grp_acc[idx] = ((const float*)ge4)[idx];
        return;
    }
    bx -= gaB;
    if (bx < gzB) {
        int idx = bx * 256 + threadIdx.x;
        gi_out[idx] = 0.f;
        return;
    }
    bx -= gzB;
    if (bx < bfB) {
        int t = bx * 256 + threadIdx.x;  // < 313*4*64 exactly
        int l = t & 63;
        int ct = (t >> 6) & 3;
        int kc = t >> 8;
        int j = ct * 16 + (l & 15);
        int kb = kc * 32 + (l >> 4) * 8;
        bf16x8 pack;
#pragma unroll
        for (int e = 0; e < 8; ++e) {
            int k = kb + e;
            float f = (k < GG_K) ? ((const float*)ge4)[(size_t)k * 64 + j] : 0.f;
            pack[e] = (short)bfc(f);
        }
        *(bf16x8*)(Bfrag + (size_t)t * 8) = pack;
        return;
    }
    bx -= bfB;
    int b = bx * 256 + threadIdx.x;
    if (b < NBUCK) cursor[b] = b * cap;
}

// ================= PHASE 2: bscatter || gg_mfma =================

static __device__ __forceinline__ void bscatter_body(const int* __restrict__ rows,
                                                     const int* __restrict__ cols,
                                                     const float* __restrict__ vals,
                                                     int* __restrict__ cursor,
                                                     int2* __restrict__ bpair,
                                                     int nE, int cap, int blk) {
    __shared__ int h[NBUCK];
    __shared__ int base[NBUCK];
    for (int i = threadIdx.x; i < NBUCK; i += 256) h[i] = 0;
    __syncthreads();
    int s = blk * ACHUNK;
    int end = s + ACHUNK; if (end > nE) end = nE;
    for (int e = s + threadIdx.x; e < end; e += 256)
        atomicAdd(&h[rows[e] >> BUCK_SHIFT], 1);
    __syncthreads();
    for (int i = threadIdx.x; i < NBUCK; i += 256) {
        int c = h[i];
        base[i] = c ? atomicAdd(&cursor[i], c) : 0;
        h[i] = 0;
    }
    __syncthreads();
    for (int e = s + threadIdx.x; e < end; e += 256) {
        int r = rows[e];
        int b = r >> BUCK_SHIFT;
        int pos = base[b] + atomicAdd(&h[b], 1);
        if (pos < (b + 1) * cap)
            bpair[pos] = make_int2(((r & (BUCK_ROWS - 1)) << 24) | cols[e],
                                   __float_as_int(vals[e]));
    }
}

static __device__ __forceinline__ void gg_mfma_body(const float* __restrict__ A,
                                                    const short* __restrict__ Bfrag,
                                                    float* __restrict__ part, int blk) {
    const int stripe = blk % GG_STRIPES;
    const int ks = blk / GG_STRIPES;  // 0..7
    const int w = threadIdx.x >> 6;
    const int l = threadIdx.x & 63;
    const int r0w = stripe * 64 + w * 16;
    int arow_i = r0w + (l & 15);
    if (arow_i > GG_K - 1) arow_i = GG_K - 1;
    const float* arow = A + (size_t)arow_i * GG_K;
    const int kg8 = (l >> 4) * 8;
    const int c0 = (ks == 0) ? 0 : 40 + 39 * (ks - 1);
    const int c1 = c0 + ((ks == 0) ? 40 : 39);
    f32x4 acc0 = {0.f, 0.f, 0.f, 0.f}, acc1 = acc0, acc2 = acc0, acc3 = acc0;
    for (int kc = c0; kc < c1; ++kc) {
        const int kbase = kc * 32 + kg8;
        bf16x8 af;
        if (kc != GG_KC - 1) {
            const float4 a0 = *(const float4*)(arow + kbase);
            const float4 a1 = *(const float4*)(arow + kbase + 4);
            af[0] = (short)bfc(a0.x); af[1] = (short)bfc(a0.y);
            af[2] = (short)bfc(a0.z); af[3] = (short)bfc(a0.w);
            af[4] = (short)bfc(a1.x); af[5] = (short)bfc(a1.y);
            af[6] = (short)bfc(a1.z); af[7] = (short)bfc(a1.w);
        } else {
#pragma unroll
            for (int e = 0; e < 8; ++e) {
                int k = kbase + e;
                af[e] = (short)bfc((k < GG_K) ? arow[k] : 0.f);
            }
        }
        const bf16x8* bp = (const bf16x8*)(Bfrag + (size_t)kc * 4 * 64 * 8);
        bf16x8 b0 = bp[0 * 64 + l];
        bf16x8 b1 = bp[1 * 64 + l];
        bf16x8 b2 = bp[2 * 64 + l];
        bf16x8 b3 = bp[3 * 64 + l];
        acc0 = __builtin_amdgcn_mfma_f32_16x16x32_bf16(af, b0, acc0, 0, 0, 0);
        acc1 = __builtin_amdgcn_mfma_f32_16x16x32_bf16(af, b1, acc1, 0, 0, 0);
        acc2 = __builtin_amdgcn_mfma_f32_16x16x32_bf16(af, b2, acc2, 0, 0, 0);
        acc3 = __builtin_amdgcn_mfma_f32_16x16x32_bf16(af, b3, acc3, 0, 0, 0);
    }
    float* po = part + (size_t)ks * GG_K * 64;
    const int orow0 = r0w + (l >> 4) * 4;
    const int ocol = l & 15;
#pragma unroll
    for (int reg = 0; reg < 4; ++reg) {
        int orow = orow0 + reg;
        if (orow < GG_K) {
            float* q = po + (size_t)orow * 64 + ocol;
            q[0]  = acc0[reg];
            q[16] = acc1[reg];
            q[32] = acc2[reg];
            q[48] = acc3[reg];
        }
    }
}

// blocks [0,bsB): bscatter | [bsB, bsB+ggB): gg_mfma
__global__ __launch_bounds__(256) void k_phase2(const int* __restrict__ rows,
                                                const int* __restrict__ cols,
                                                const float* __restrict__ vals,
                                                int* __restrict__ cursor,
                                                int2* __restrict__ bpair, int nE, int cap,
                                                const float* __restrict__ A,
                                                const short* __restrict__ Bfrag,
                                                float* __restrict__ part, int bsB) {
    if (blockIdx.x < bsB)
        bscatter_body(rows, cols, vals, cursor, bpair, nE, cap, blockIdx.x);
    else
        gg_mfma_body(A, Bfrag, part, blockIdx.x - bsB);
}

// ================= PHASE 3: bcsr || gi_spmm =================

static __device__ __forceinline__ void bcsr_body(const int* __restrict__ cursor,
                                                 const int2* __restrict__ bpair,
                                                 int2* __restrict__ ep,
                                                 int* __restrict__ rp, int* __restrict__ cnt,
                                                 int cap, int b) {
    __shared__ int hist[256];
    __shared__ int sc[256];
    const int tid = threadIdx.x;
    const int s = b * cap;
    int e_ = cursor[b];
    if (e_ > s + cap) e_ = s + cap;
    hist[tid] = 0;
    __syncthreads();
    for (int i = s + tid; i < e_; i += 256)
        atomicAdd(&hist[((unsigned)bpair[i].x) >> 24], 1);
    __syncthreads();
    int v = hist[tid];
    sc[tid] = v;
    __syncthreads();
    for (int off = 1; off < 256; off <<= 1) {
        int t = (tid >= off) ? sc[tid - off] : 0;
        __syncthreads();
        if (tid >= off) sc[tid] += t;
        __syncthreads();
    }
    int excl = sc[tid] - v;
    int gr = (b << BUCK_SHIFT) + tid;
    if (gr < NHG) { rp[gr] = s + excl; cnt[gr] = v; }
    hist[tid] = excl;
    __syncthreads();
    for (int i = s + tid; i < e_; i += 256) {
        int2 p = bpair[i];
        unsigned pk = (unsigned)p.x;
        int pos = atomicAdd(&hist[pk >> 24], 1);
        ep[s + pos] = make_int2((int)(pk & 0xFFFFFFu), p.y);
    }
}

static __device__ __forceinline__ void gi_body(const int* __restrict__ rows,
                                               const int* __restrict__ cols,
                                               const float* __restrict__ vals,
                                               const float* __restrict__ ge,
                                               const float* __restrict__ ie,
                                               float* __restrict__ out, int nE,
                                               int blk, int nblk) {
    int lane = threadIdx.x & 63;
    long wslot = (long)blk * 4 + (threadIdx.x >> 6);
    const long nslots = (long)nblk * 4;
    for (long base = wslot * 64; base < nE; base += nslots * 64) {
        long e = base + lane;
        int r = (e < nE) ? rows[e] : 0x7fffffff;
        bool ok = (r < G_N);
        int c = 0;
        float v = 0.f;
        if (ok) { c = cols[e]; v = vals[e]; }
        unsigned long long mask = __ballot(ok);
        while (mask) {
            int srcl = __ffsll(mask) - 1;
            mask &= mask - 1;
            int rr = __shfl(r, srcl, 64);
            int cc = __shfl(c, srcl, 64);
            float vv = __shfl(v, srcl, 64);
            const float* sp = (cc < G_N) ? (ge + (size_t)cc * 64) : (ie + (size_t)(cc - G_N) * 64);
            atomicAdd(&out[(size_t)rr * 64 + lane], vv * sp[lane]);
        }
    }
}

// blocks [0,NBUCK): bcsr | [NBUCK, NBUCK+giB): gi
__global__ __launch_bounds__(256) void k_phase3(const int* __restrict__ cursor,
                                                const int2* __restrict__ bpair,
                                                int2* __restrict__ ep,
                                                int* __restrict__ rp, int* __restrict__ cnt,
                                                int cap,
                                                const int* __restrict__ grows,
                                                const int* __restrict__ gcols,
                                                const float* __restrict__ gvals,
                                                const float* __restrict__ ge,
                                                const float* __restrict__ ie,
                                                float* __restrict__ gi_out, int gnE, int giB) {
    if (blockIdx.x < NBUCK)
        bcsr_body(cursor, bpair, ep, rp, cnt, cap, blockIdx.x);
    else
        gi_body(grows, gcols, gvals, ge, ie, gi_out, gnE, blockIdx.x - NBUCK, giB);
}

// ---------------- SpMM: 2 rows per wave, 32 lanes x u32 (2 bf16 dims) ----------------

static __device__ __forceinline__ void spmm_row2(const int2* __restrict__ ep, int s, int n,
                                                 int nmax, const unsigned* __restrict__ x32,
                                                 int sub, float& ax, float& ay) {
    ax = 0.f; ay = 0.f;
    for (int i = 0; i < nmax; i += 8) {
        int2 e[8];
#pragma unroll
        for (int j = 0; j < 8; ++j) {
            int k = i + j;
            int kk = (k < n) ? k : (n > 0 ? n - 1 : 0);
            e[j] = ep[s + kk];
            if (k >= n) e[j].y = 0;
        }
        unsigned xv[8];
#pragma unroll
        for (int j = 0; j < 8; ++j)
            xv[j] = x32[(size_t)e[j].x * 32 + sub];
#pragma unroll
        for (int j = 0; j < 8; ++j) {
            float v = __int_as_float(e[j].y);
            ax += v * blo(xv[j]);
            ay += v * bhi(xv[j]);
        }
    }
}

__global__ void k_spmm2(const int* __restrict__ rp, const int* __restrict__ cnt,
                        const int2* __restrict__ ep, const unsigned* __restrict__ x32,
                        unsigned* __restrict__ out32, float* __restrict__ grp_acc,
                        const int* __restrict__ ui, float* __restrict__ usr_acc,
                        int spmmBlocks) {
    if (blockIdx.x >= spmmBlocks) {
        int idx = (blockIdx.x - spmmBlocks) * 256 + threadIdx.x;  // < B_N*32
        int b = idx >> 5, d = idx & 31;
        unsigned u = x32[(size_t)ui[b] * 32 + d];
        float2* g = (float2*)usr_acc + ((size_t)b * 32 + d);
        float2 t = *g;
        t.x += blo(u); t.y += bhi(u);
        *g = t;
        return;
    }
    int wid = threadIdx.x >> 6;
    int lane = threadIdx.x & 63;
    int half = lane >> 5, sub = lane & 31;
    int r = blockIdx.x * 8 + wid * 2 + half;
    bool active = (r < NHG);
    int rr = active ? r : NHG - 1;
    int s = rp[rr];
    int n = active ? cnt[rr] : 0;
    int nmax = n;
    nmax = max(nmax, __shfl_xor(nmax, 32, 64));
    float ax, ay;
    spmm_row2(ep, s, n, nmax, x32, sub, ax, ay);
    if (active) {
        out32[(size_t)r * 32 + sub] = bfc(ax) | (bfc(ay) << 16);
        if (r >= U_N) {
            float2* g = (float2*)grp_acc + ((size_t)(r - U_N) * 32 + sub);
            float2 t = *g;
            t.x += ax; t.y += ay;
            *g = t;
        }
    }
}

__global__ void k_spmm_final(const int* __restrict__ rp, const int* __restrict__ cnt,
                             const int2* __restrict__ ep, const unsigned* __restrict__ x32,
                             const int* __restrict__ ui,
                             float* __restrict__ grp_acc, float* __restrict__ usr_acc,
                             int taskBlocks) {
    if (blockIdx.x >= taskBlocks) {
        int idx = (blockIdx.x - taskBlocks) * 256 + threadIdx.x;  // < B_N*32
        int b = idx >> 5, d = idx & 31;
        unsigned u = x32[(size_t)ui[b] * 32 + d];
        float2* g = (float2*)usr_acc + ((size_t)b * 32 + d);
        float2 t = *g;
        t.x += blo(u); t.y += bhi(u);
        *g = t;
        return;
    }
    int wid = threadIdx.x >> 6;
    int lane = threadIdx.x & 63;
    int half = lane >> 5, sub = lane & 31;
    int t = blockIdx.x * 8 + wid * 2 + half;
    bool active = (t < G_N + B_N);
    int tt = active ? t : 0;
    int r = (tt < G_N) ? (U_N + tt) : ui[tt - G_N];
    int s = rp[r];
    int n = active ? cnt[r] : 0;
    int nmax = n;
    nmax = max(nmax, __shfl_xor(nmax, 32, 64));
    float ax, ay;
    spmm_row2(ep, s, n, nmax, x32, sub, ax, ay);
    if (active) {
        float2* g = (tt < G_N) ? ((float2*)grp_acc + ((size_t)tt * 32 + sub))
                               : ((float2*)usr_acc + ((size_t)(tt - G_N) * 32 + sub));
        float2 v = *g;
        v.x += ax; v.y += ay;
        *g = v;
    }
}

// ---------------- finalize groups (with inline 8-way gg reduce) ----------------

__global__ void k_finalize(const float* __restrict__ ga, const float* __restrict__ gi,
                           const float* __restrict__ gg_part, const float* __restrict__ hw,
                           const float* __restrict__ hb, const float* __restrict__ lw,
                           const float* __restrict__ lb, const float* __restrict__ ow,
                           const float* __restrict__ ob, float* __restrict__ gf) {
    int g = blockIdx.x * 4 + (threadIdx.x >> 6);
    if (g >= G_N) return;
    int lane = threadIdx.x & 63;
    size_t o = (size_t)g * 64 + lane;
    float hgv = ga[o] * 0.25f;
    float giv = gi[o];
    const size_t S = (size_t)GG_K * 64;
    float ggv = 0.f;
#pragma unroll
    for (int p = 0; p < GG_SPLIT; ++p) ggv += gg_part[p * S + o];
    float d1 = hgv * hw[lane], d2 = giv * lw[lane], d3 = ggv * ow[lane];
#pragma unroll
    for (int off = 32; off; off >>= 1) {
        d1 += __shfl_xor(d1, off, 64);
        d2 += __shfl_xor(d2, off, 64);
        d3 += __shfl_xor(d3, off, 64);
    }
    float hc = sigmoidf_(d1 + hb[0]);
    float lc = sigmoidf_(d2 + lb[0]);
    float oc = sigmoidf_(d3 + ob[0]);
    gf[o] = hc * hgv + lc * giv + oc * ggv;
}

// ---------------- gather outputs (f32) ----------------

__global__ void k_gather_out(const int* __restrict__ ui, const int* __restrict__ pg,
                             const int* __restrict__ ng, const float* __restrict__ ua,
                             const float* __restrict__ gf, const float* __restrict__ ue,
                             const float* __restrict__ ge, float* __restrict__ out) {
    int idx = blockIdx.x * 256 + threadIdx.x;
    if (idx >= B_N * 64) return;
    int b = idx >> 6, d = idx & 63;
    const int S = B_N * 64;
    int u = ui[b], p = pg[b], q = ng[b];
    out[idx]         = ua[idx] * 0.25f;
    out[S + idx]     = gf[(size_t)p * 64 + d];
    out[2 * S + idx] = gf[(size_t)q * 64 + d];
    out[3 * S + idx] = ue[(size_t)u * 64 + d];
    out[4 * S + idx] = ge[(size_t)p * 64 + d];
    out[5 * S + idx] = ge[(size_t)q * 64 + d];
}

extern "C" void kernel_launch(void* const* d_in, const int* in_sizes, int n_in,
                              void* d_out, int out_size, void* d_ws, size_t ws_size,
                              hipStream_t stream) {
    const int*   ui        = (const int*)d_in[0];
    const int*   pg        = (const int*)d_in[1];
    const int*   ng        = (const int*)d_in[2];
    const int*   hg_rows   = (const int*)d_in[3];
    const int*   hg_cols   = (const int*)d_in[4];
    const float* hg_vals   = (const float*)d_in[5];
    const int*   gi_rows   = (const int*)d_in[6];
    const int*   gi_cols   = (const int*)d_in[7];
    const float* gi_vals   = (const float*)d_in[8];
    const float* gg_graph  = (const float*)d_in[9];
    const float* user_emb  = (const float*)d_in[10];
    const float* item_emb  = (const float*)d_in[11];
    const float* group_emb = (const float*)d_in[12];
    const float* hyper_w   = (const float*)d_in[13];
    const float* hyper_b   = (const float*)d_in[14];
    const float* lgcn_w    = (const float*)d_in[15];
    const float* lgcn_b    = (const float*)d_in[16];
    const float* ovl_w     = (const float*)d_in[17];
    const float* ovl_b     = (const float*)d_in[18];
    const int E_HG = in_sizes[3];
    const int E_GI = in_sizes[6];

    const int nblkA = (E_HG + ACHUNK - 1) / ACHUNK;
    int cap = (E_HG + NBUCK - 1) / NBUCK;
    cap = cap + cap / 4 + 64;
    cap = (cap + 63) & ~63;

    // ---- workspace layout (~135 MB; ws is ~1.6 GB) ----
    char* ws = (char*)d_ws;
    size_t off = 0;
    auto alloc = [&](size_t bytes) -> char* {
        char* p = ws + off;
        off += (bytes + 255) & ~(size_t)255;
        return p;
    };
    int*   cursor  = (int*)alloc((size_t)NBUCK * 4);
    int2*  bpair   = (int2*)alloc((size_t)NBUCK * cap * 8);
    int2*  ep      = (int2*)alloc((size_t)NBUCK * cap * 8 + 1024);
    int*   rp      = (int*)alloc((size_t)NHG * 4);
    int*   cnt     = (int*)alloc((size_t)NHG * 4);
    __hip_bfloat16* curA = (__hip_bfloat16*)alloc((size_t)NHG * 64 * 2);
    __hip_bfloat16* curB = (__hip_bfloat16*)alloc((size_t)NHG * 64 * 2);
    float* grp_acc = (float*)alloc((size_t)G_N * 64 * 4);
    float* gi_out  = (float*)alloc((size_t)G_N * 64 * 4);
    float* grp_fin = (float*)alloc((size_t)G_N * 64 * 4);
    float* usr_acc = (float*)alloc((size_t)B_N * 64 * 4);
    short* Bfrag   = (short*)alloc((size_t)GG_KC * 4 * 64 * 8 * 2);
    float* gg_part = (float*)alloc((size_t)GG_SPLIT * GG_K * 64 * 4);
    (void)ws_size; (void)n_in; (void)out_size;

    // ---- P1: all independent prep ----
    const int cvtB = (NHG * 16) / 256;       // 13125
    const int uaB  = (B_N * 64) / 256;       // 2048
    const int gaB  = (G_N * 64) / 256;       // 2500
    const int gzB  = (G_N * 64) / 256;       // 2500
    const int bfB  = GG_KC;                  // 313
    k_phase1<<<cvtB + uaB + gaB + gzB + bfB + 4, 256, 0, stream>>>(
        (const float4*)user_emb, (const float4*)group_emb, (ushort4*)curB, ui, usr_acc,
        grp_acc, gi_out, Bfrag, cursor, cap, cvtB, uaB, gaB, gzB, bfB);

    // ---- P2: bscatter || gg_mfma ----
    k_phase2<<<nblkA + GG_STRIPES * GG_SPLIT, 256, 0, stream>>>(
        hg_rows, hg_cols, hg_vals, cursor, bpair, E_HG, cap,
        gg_graph, Bfrag, gg_part, nblkA);

    // ---- P3: bcsr || gi_spmm ----
    const int giB = 2048;
    k_phase3<<<NBUCK + giB, 256, 0, stream>>>(cursor, bpair, ep, rp, cnt, cap,
                                              gi_rows, gi_cols, gi_vals,
                                              group_emb, item_emb, gi_out, E_GI, giB);

    const int spmmB = (NHG + 7) / 8;
    const int uaExt = (B_N * 32) / 256;  // 1024 blocks

    // P4: layer 1: curB -> curA (grp_acc fused)
    k_spmm2<<<spmmB, 256, 0, stream>>>(rp, cnt, ep, (const unsigned*)curB,
                                       (unsigned*)curA, grp_acc, nullptr, nullptr, spmmB);
    // P5: layer 2: curA -> curB (grp_acc fused; ext: usr_acc += curA[ui])
    k_spmm2<<<spmmB + uaExt, 256, 0, stream>>>(rp, cnt, ep, (const unsigned*)curA,
                                               (unsigned*)curB, grp_acc, ui, usr_acc, spmmB);
    // P6: layer 3 targeted; ext: usr_acc += curB[ui]
    const int taskB = (G_N + B_N + 7) / 8;
    k_spmm_final<<<taskB + uaExt, 256, 0, stream>>>(rp, cnt, ep, (const unsigned*)curB, ui,
                                                    grp_acc, usr_acc, taskB);

    // P7 + P8: finalize (+gg reduce) + gather
    k_finalize<<<(G_N + 3) / 4, 256, 0, stream>>>(grp_acc, gi_out, gg_part, hyper_w, hyper_b,
                                                  lgcn_w, lgcn_b, ovl_w, ovl_b, grp_fin);
    k_gather_out<<<(B_N * 64 + 255) / 256, 256, 0, stream>>>(ui, pg, ng, usr_acc, grp_fin,
                                                             user_emb, group_emb,
                                                             (float*)d_out);
}

// Round 11
// 443.638 us; speedup vs baseline: 8.8680x; 1.0639x over previous
//
#include <hip/hip_runtime.h>
#include <hip/hip_bf16.h>

#define U_N 200000
#define I_N 100000
#define G_N 10000
#define B_N 8192
#define NHG (U_N + G_N)   /* 210000 */
#define GG_K 10000
#define GG_KC 313         /* ceil(10000/32) k-chunks */
#define GG_STRIPES 157    /* ceil(10000/64) row stripes */
#define GG_SPLIT 8

#define BUCK_SHIFT 8
#define BUCK_ROWS 256
#define NBUCK 821         /* ceil(NHG/256) */
#define ACHUNK 12288      /* edges per partition block */

typedef __attribute__((ext_vector_type(8))) short bf16x8;
typedef __attribute__((ext_vector_type(4))) float f32x4;

static __device__ __forceinline__ float sigmoidf_(float x) {
    return 1.0f / (1.0f + __expf(-x));
}

// f32 -> bf16 bits, round-to-nearest-even
static __device__ __forceinline__ unsigned bfc(float x) {
    unsigned u = __float_as_uint(x);
    return (u + 0x7fffu + ((u >> 16) & 1u)) >> 16;
}
static __device__ __forceinline__ float blo(unsigned u) { return __uint_as_float(u << 16); }
static __device__ __forceinline__ float bhi(unsigned u) { return __uint_as_float(u & 0xffff0000u); }
static __device__ __forceinline__ float bsf(unsigned short u) {
    return __uint_as_float((unsigned)u << 16);
}

// ================= PHASE 1: bfrag + cursor init (tiny) =================
__global__ void k_phase1(const float* __restrict__ ge, short* __restrict__ Bfrag,
                         int* __restrict__ cursor, int cap, int bfB) {
    int bx = blockIdx.x;
    if (bx < bfB) {
        int t = bx * 256 + threadIdx.x;  // < 313*4*64 exactly
        int l = t & 63;
        int ct = (t >> 6) & 3;
        int kc = t >> 8;
        int j = ct * 16 + (l & 15);
        int kb = kc * 32 + (l >> 4) * 8;
        bf16x8 pack;
#pragma unroll
        for (int e = 0; e < 8; ++e) {
            int k = kb + e;
            float f = (k < GG_K) ? ge[(size_t)k * 64 + j] : 0.f;
            pack[e] = (short)bfc(f);
        }
        *(bf16x8*)(Bfrag + (size_t)t * 8) = pack;
        return;
    }
    int b = (bx - bfB) * 256 + threadIdx.x;
    if (b < NBUCK) cursor[b] = b * cap;
}

// ================= PHASE 2: bscatter || gg_mfma || cvt || inits =================

static __device__ __forceinline__ void bscatter_body(const int* __restrict__ rows,
                                                     const int* __restrict__ cols,
                                                     const float* __restrict__ vals,
                                                     int* __restrict__ cursor,
                                                     int2* __restrict__ bpair,
                                                     int nE, int cap, int blk) {
    __shared__ int h[NBUCK];
    __shared__ int base[NBUCK];
    for (int i = threadIdx.x; i < NBUCK; i += 256) h[i] = 0;
    __syncthreads();
    int s = blk * ACHUNK;
    int end = s + ACHUNK; if (end > nE) end = nE;
    for (int e = s + threadIdx.x; e < end; e += 256)
        atomicAdd(&h[rows[e] >> BUCK_SHIFT], 1);
    __syncthreads();
    for (int i = threadIdx.x; i < NBUCK; i += 256) {
        int c = h[i];
        base[i] = c ? atomicAdd(&cursor[i], c) : 0;
        h[i] = 0;
    }
    __syncthreads();
    for (int e = s + threadIdx.x; e < end; e += 256) {
        int r = rows[e];
        int b = r >> BUCK_SHIFT;
        int pos = base[b] + atomicAdd(&h[b], 1);
        if (pos < (b + 1) * cap)
            bpair[pos] = make_int2(((r & (BUCK_ROWS - 1)) << 24) | cols[e],
                                   __float_as_int(vals[e]));
    }
}

static __device__ __forceinline__ void gg_mfma_body(const float* __restrict__ A,
                                                    const short* __restrict__ Bfrag,
                                                    float* __restrict__ part, int blk) {
    const int stripe = blk % GG_STRIPES;
    const int ks = blk / GG_STRIPES;  // 0..7
    const int w = threadIdx.x >> 6;
    const int l = threadIdx.x & 63;
    const int r0w = stripe * 64 + w * 16;
    int arow_i = r0w + (l & 15);
    if (arow_i > GG_K - 1) arow_i = GG_K - 1;
    const float* arow = A + (size_t)arow_i * GG_K;
    const int kg8 = (l >> 4) * 8;
    const int c0 = (ks == 0) ? 0 : 40 + 39 * (ks - 1);
    const int c1 = c0 + ((ks == 0) ? 40 : 39);
    f32x4 acc0 = {0.f, 0.f, 0.f, 0.f}, acc1 = acc0, acc2 = acc0, acc3 = acc0;
    for (int kc = c0; kc < c1; ++kc) {
        const int kbase = kc * 32 + kg8;
        bf16x8 af;
        if (kc != GG_KC - 1) {
            const float4 a0 = *(const float4*)(arow + kbase);
            const float4 a1 = *(const float4*)(arow + kbase + 4);
            af[0] = (short)bfc(a0.x); af[1] = (short)bfc(a0.y);
            af[2] = (short)bfc(a0.z); af[3] = (short)bfc(a0.w);
            af[4] = (short)bfc(a1.x); af[5] = (short)bfc(a1.y);
            af[6] = (short)bfc(a1.z); af[7] = (short)bfc(a1.w);
        } else {
#pragma unroll
            for (int e = 0; e < 8; ++e) {
                int k = kbase + e;
                af[e] = (short)bfc((k < GG_K) ? arow[k] : 0.f);
            }
        }
        const bf16x8* bp = (const bf16x8*)(Bfrag + (size_t)kc * 4 * 64 * 8);
        bf16x8 b0 = bp[0 * 64 + l];
        bf16x8 b1 = bp[1 * 64 + l];
        bf16x8 b2 = bp[2 * 64 + l];
        bf16x8 b3 = bp[3 * 64 + l];
        acc0 = __builtin_amdgcn_mfma_f32_16x16x32_bf16(af, b0, acc0, 0, 0, 0);
        acc1 = __builtin_amdgcn_mfma_f32_16x16x32_bf16(af, b1, acc1, 0, 0, 0);
        acc2 = __builtin_amdgcn_mfma_f32_16x16x32_bf16(af, b2, acc2, 0, 0, 0);
        acc3 = __builtin_amdgcn_mfma_f32_16x16x32_bf16(af, b3, acc3, 0, 0, 0);
    }
    float* po = part + (size_t)ks * GG_K * 64;
    const int orow0 = r0w + (l >> 4) * 4;
    const int ocol = l & 15;
#pragma unroll
    for (int reg = 0; reg < 4; ++reg) {
        int orow = orow0 + reg;
        if (orow < GG_K) {
            float* q = po + (size_t)orow * 64 + ocol;
            q[0]  = acc0[reg];
            q[16] = acc1[reg];
            q[32] = acc2[reg];
            q[48] = acc3[reg];
        }
    }
}

// segments: [0,bsB) bscatter | [+ggB) gg | [+cvtB) cvt | [+uaB) ua init
//         | [+gaB) grp_acc init | [+gzB) gi zero
__global__ __launch_bounds__(256) void k_phase2(
    const int* __restrict__ rows, const int* __restrict__ cols,
    const float* __restrict__ vals, int* __restrict__ cursor,
    int2* __restrict__ bpair, int nE, int cap,
    const float* __restrict__ A, const short* __restrict__ Bfrag,
    float* __restrict__ part,
    const float4* __restrict__ ue4, const float4* __restrict__ ge4,
    ushort4* __restrict__ out4, const int* __restrict__ ui,
    float* __restrict__ ua, float* __restrict__ grp_acc, float* __restrict__ gi_out,
    int bsB, int ggB, int cvtB, int uaB, int gaB) {
    int bx = blockIdx.x;
    if (bx < bsB) { bscatter_body(rows, cols, vals, cursor, bpair, nE, cap, bx); return; }
    bx -= bsB;
    if (bx < ggB) { gg_mfma_body(A, Bfrag, part, bx); return; }
    bx -= ggB;
    if (bx < cvtB) {
        int i = bx * 256 + threadIdx.x;  // < NHG*16 exactly
        float4 f = (i < U_N * 16) ? ue4[i] : ge4[i - U_N * 16];
        ushort4 o;
        o.x = (unsigned short)bfc(f.x);
        o.y = (unsigned short)bfc(f.y);
        o.z = (unsigned short)bfc(f.z);
        o.w = (unsigned short)bfc(f.w);
        out4[i] = o;
        return;
    }
    bx -= cvtB;
    if (bx < uaB) {
        int idx = bx * 256 + threadIdx.x;  // < B_N*64
        int b = idx >> 6, d = idx & 63;
        ua[idx] = ((const float*)ue4)[(size_t)ui[b] * 64 + d];
        return;
    }
    bx -= uaB;
    if (bx < gaB) {
        int idx = bx * 256 + threadIdx.x;  // < G_N*64
        grp_acc[idx] = ((const float*)ge4)[idx];
        return;
    }
    bx -= gaB;
    int idx = bx * 256 + threadIdx.x;
    gi_out[idx] = 0.f;
}

// ================= PHASE 3: bcsr || gi_spmm =================

static __device__ __forceinline__ void bcsr_body(const int* __restrict__ cursor,
                                                 const int2* __restrict__ bpair,
                                                 int2* __restrict__ ep,
                                                 int* __restrict__ rp, int* __restrict__ cnt,
                                                 int cap, int b) {
    __shared__ int hist[256];
    __shared__ int sc[256];
    const int tid = threadIdx.x;
    const int s = b * cap;
    int e_ = cursor[b];
    if (e_ > s + cap) e_ = s + cap;
    hist[tid] = 0;
    __syncthreads();
    for (int i = s + tid; i < e_; i += 256)
        atomicAdd(&hist[((unsigned)bpair[i].x) >> 24], 1);
    __syncthreads();
    int v = hist[tid];
    sc[tid] = v;
    __syncthreads();
    for (int off = 1; off < 256; off <<= 1) {
        int t = (tid >= off) ? sc[tid - off] : 0;
        __syncthreads();
        if (tid >= off) sc[tid] += t;
        __syncthreads();
    }
    int excl = sc[tid] - v;
    int gr = (b << BUCK_SHIFT) + tid;
    if (gr < NHG) { rp[gr] = s + excl; cnt[gr] = v; }
    hist[tid] = excl;
    __syncthreads();
    for (int i = s + tid; i < e_; i += 256) {
        int2 p = bpair[i];
        unsigned pk = (unsigned)p.x;
        int pos = atomicAdd(&hist[pk >> 24], 1);
        ep[s + pos] = make_int2((int)(pk & 0xFFFFFFu), p.y);
    }
}

static __device__ __forceinline__ void gi_body(const int* __restrict__ rows,
                                               const int* __restrict__ cols,
                                               const float* __restrict__ vals,
                                               const float* __restrict__ ge,
                                               const float* __restrict__ ie,
                                               float* __restrict__ out, int nE,
                                               int blk, int nblk) {
    int lane = threadIdx.x & 63;
    long wslot = (long)blk * 4 + (threadIdx.x >> 6);
    const long nslots = (long)nblk * 4;
    for (long base = wslot * 64; base < nE; base += nslots * 64) {
        long e = base + lane;
        int r = (e < nE) ? rows[e] : 0x7fffffff;
        bool ok = (r < G_N);
        int c = 0;
        float v = 0.f;
        if (ok) { c = cols[e]; v = vals[e]; }
        unsigned long long mask = __ballot(ok);
        while (mask) {
            int srcl = __ffsll(mask) - 1;
            mask &= mask - 1;
            int rr = __shfl(r, srcl, 64);
            int cc = __shfl(c, srcl, 64);
            float vv = __shfl(v, srcl, 64);
            const float* sp = (cc < G_N) ? (ge + (size_t)cc * 64) : (ie + (size_t)(cc - G_N) * 64);
            atomicAdd(&out[(size_t)rr * 64 + lane], vv * sp[lane]);
        }
    }
}

__global__ __launch_bounds__(256) void k_phase3(const int* __restrict__ cursor,
                                                const int2* __restrict__ bpair,
                                                int2* __restrict__ ep,
                                                int* __restrict__ rp, int* __restrict__ cnt,
                                                int cap,
                                                const int* __restrict__ grows,
                                                const int* __restrict__ gcols,
                                                const float* __restrict__ gvals,
                                                const float* __restrict__ ge,
                                                const float* __restrict__ ie,
                                                float* __restrict__ gi_out, int gnE, int giB) {
    if (blockIdx.x < NBUCK)
        bcsr_body(cursor, bpair, ep, rp, cnt, cap, blockIdx.x);
    else
        gi_body(grows, gcols, gvals, ge, ie, gi_out, gnE, blockIdx.x - NBUCK, giB);
}

// ---------------- SpMM: 4 rows/wave, 16 lanes x ushort4 (4 bf16 dims) ----------------

static __device__ __forceinline__ void spmm_row4(const int2* __restrict__ ep, int s, int n,
                                                 int nmax, const ushort4* __restrict__ x8,
                                                 int sub, float4& acc) {
    acc.x = 0.f; acc.y = 0.f; acc.z = 0.f; acc.w = 0.f;
    for (int i = 0; i < nmax; i += 8) {
        int2 e[8];
#pragma unroll
        for (int j = 0; j < 8; ++j) {
            int k = i + j;
            int kk = (k < n) ? k : (n > 0 ? n - 1 : 0);
            e[j] = ep[s + kk];
            if (k >= n) { e[j].y = 0; e[j].x = 0; }  // clamp col too (poison safety)
        }
        ushort4 xv[8];
#pragma unroll
        for (int j = 0; j < 8; ++j)
            xv[j] = x8[(size_t)e[j].x * 16 + sub];
#pragma unroll
        for (int j = 0; j < 8; ++j) {
            float v = __int_as_float(e[j].y);
            acc.x += v * bsf(xv[j].x);
            acc.y += v * bsf(xv[j].y);
            acc.z += v * bsf(xv[j].z);
            acc.w += v * bsf(xv[j].w);
        }
    }
}

static __device__ __forceinline__ int slotmax(int n) {
    int m = max(n, __shfl_xor(n, 16, 64));
    return max(m, __shfl_xor(m, 32, 64));
}

// layers 1/2: 16 rows/block; grid ext: usr_acc += x[ui[b]] (ushort4 granularity)
__global__ void k_spmm4(const int* __restrict__ rp, const int* __restrict__ cnt,
                        const int2* __restrict__ ep, const ushort4* __restrict__ x8,
                        ushort4* __restrict__ out8, float* __restrict__ grp_acc,
                        const int* __restrict__ ui, float* __restrict__ usr_acc,
                        int spmmBlocks) {
    if (blockIdx.x >= spmmBlocks) {
        int idx = (blockIdx.x - spmmBlocks) * 256 + threadIdx.x;  // < B_N*16
        int b = idx >> 4, d = idx & 15;
        ushort4 u = x8[(size_t)ui[b] * 16 + d];
        float4* g = (float4*)usr_acc + ((size_t)b * 16 + d);
        float4 t = *g;
        t.x += bsf(u.x); t.y += bsf(u.y); t.z += bsf(u.z); t.w += bsf(u.w);
        *g = t;
        return;
    }
    int wid = threadIdx.x >> 6;
    int lane = threadIdx.x & 63;
    int slot = lane >> 4, sub = lane & 15;
    int r = blockIdx.x * 16 + wid * 4 + slot;  // NHG = 16*13125, exact
    int s = rp[r];
    int n = cnt[r];
    int nmax = slotmax(n);
    float4 a;
    spmm_row4(ep, s, n, nmax, x8, sub, a);
    ushort4 o;
    o.x = (unsigned short)bfc(a.x);
    o.y = (unsigned short)bfc(a.y);
    o.z = (unsigned short)bfc(a.z);
    o.w = (unsigned short)bfc(a.w);
    out8[(size_t)r * 16 + sub] = o;
    if (r >= U_N) {
        float4* g = (float4*)grp_acc + ((size_t)(r - U_N) * 16 + sub);
        float4 t = *g;
        t.x += a.x; t.y += a.y; t.z += a.z; t.w += a.w;
        *g = t;
    }
}

// layer 3 targeted; grid ext: usr_acc += x[ui[b]]
__global__ void k_spmm4_final(const int* __restrict__ rp, const int* __restrict__ cnt,
                              const int2* __restrict__ ep, const ushort4* __restrict__ x8,
                              const int* __restrict__ ui,
                              float* __restrict__ grp_acc, float* __restrict__ usr_acc,
                              int taskBlocks) {
    if (blockIdx.x >= taskBlocks) {
        int idx = (blockIdx.x - taskBlocks) * 256 + threadIdx.x;  // < B_N*16
        int b = idx >> 4, d = idx & 15;
        ushort4 u = x8[(size_t)ui[b] * 16 + d];
        float4* g = (float4*)usr_acc + ((size_t)b * 16 + d);
        float4 t = *g;
        t.x += bsf(u.x); t.y += bsf(u.y); t.z += bsf(u.z); t.w += bsf(u.w);
        *g = t;
        return;
    }
    int wid = threadIdx.x >> 6;
    int lane = threadIdx.x & 63;
    int slot = lane >> 4, sub = lane & 15;
    int t = blockIdx.x * 16 + wid * 4 + slot;
    bool active = (t < G_N + B_N);
    int tt = active ? t : 0;
    int r = (tt < G_N) ? (U_N + tt) : ui[tt - G_N];
    int s = rp[r];
    int n = active ? cnt[r] : 0;
    int nmax = slotmax(n);
    float4 a;
    spmm_row4(ep, s, n, nmax, x8, sub, a);
    if (active) {
        float4* g = (tt < G_N) ? ((float4*)grp_acc + ((size_t)tt * 16 + sub))
                               : ((float4*)usr_acc + ((size_t)(tt - G_N) * 16 + sub));
        float4 v = *g;
        v.x += a.x; v.y += a.y; v.z += a.z; v.w += a.w;
        *g = v;
    }
}

// ---------------- fused finalize + gather (one wave per batch element) ----------------

__global__ void k_gather_fin(const int* __restrict__ ui, const int* __restrict__ pg,
                             const int* __restrict__ ng, const float* __restrict__ ua,
                             const float* __restrict__ ga, const float* __restrict__ gi_out,
                             const float* __restrict__ gg_part,
                             const float* __restrict__ hw, const float* __restrict__ hb,
                             const float* __restrict__ lw, const float* __restrict__ lb,
                             const float* __restrict__ ow, const float* __restrict__ ob,
                             const float* __restrict__ ue, const float* __restrict__ ge,
                             float* __restrict__ out) {
    int wid = threadIdx.x >> 6, lane = threadIdx.x & 63;
    int b = blockIdx.x * 4 + wid;  // B_N = 4*2048, exact
    const int S = B_N * 64;
    int u = ui[b], p = pg[b], q = ng[b];
    int idx = b * 64 + lane;
    out[idx]         = ua[idx] * 0.25f;
    out[3 * S + idx] = ue[(size_t)u * 64 + lane];
    out[4 * S + idx] = ge[(size_t)p * 64 + lane];
    out[5 * S + idx] = ge[(size_t)q * 64 + lane];
    const size_t SS = (size_t)G_N * 64;
    float hwv = hw[lane], lwv = lw[lane], owv = ow[lane];
    float hb0 = hb[0], lb0 = lb[0], ob0 = ob[0];
#pragma unroll
    for (int which = 0; which < 2; ++which) {
        int g = which ? q : p;
        size_t o = (size_t)g * 64 + lane;
        float hgv = ga[o] * 0.25f;
        float giv = gi_out[o];
        float ggv = 0.f;
#pragma unroll
        for (int k = 0; k < GG_SPLIT; ++k) ggv += gg_part[k * SS + o];
        float d1 = hgv * hwv, d2 = giv * lwv, d3 = ggv * owv;
#pragma unroll
        for (int off2 = 32; off2; off2 >>= 1) {
            d1 += __shfl_xor(d1, off2, 64);
            d2 += __shfl_xor(d2, off2, 64);
            d3 += __shfl_xor(d3, off2, 64);
        }
        float val = sigmoidf_(d1 + hb0) * hgv + sigmoidf_(d2 + lb0) * giv
                  + sigmoidf_(d3 + ob0) * ggv;
        out[(which ? 2 * S : S) + idx] = val;
    }
}

extern "C" void kernel_launch(void* const* d_in, const int* in_sizes, int n_in,
                              void* d_out, int out_size, void* d_ws, size_t ws_size,
                              hipStream_t stream) {
    const int*   ui        = (const int*)d_in[0];
    const int*   pg        = (const int*)d_in[1];
    const int*   ng        = (const int*)d_in[2];
    const int*   hg_rows   = (const int*)d_in[3];
    const int*   hg_cols   = (const int*)d_in[4];
    const float* hg_vals   = (const float*)d_in[5];
    const int*   gi_rows   = (const int*)d_in[6];
    const int*   gi_cols   = (const int*)d_in[7];
    const float* gi_vals   = (const float*)d_in[8];
    const float* gg_graph  = (const float*)d_in[9];
    const float* user_emb  = (const float*)d_in[10];
    const float* item_emb  = (const float*)d_in[11];
    const float* group_emb = (const float*)d_in[12];
    const float* hyper_w   = (const float*)d_in[13];
    const float* hyper_b   = (const float*)d_in[14];
    const float* lgcn_w    = (const float*)d_in[15];
    const float* lgcn_b    = (const float*)d_in[16];
    const float* ovl_w     = (const float*)d_in[17];
    const float* ovl_b     = (const float*)d_in[18];
    const int E_HG = in_sizes[3];
    const int E_GI = in_sizes[6];

    const int nblkA = (E_HG + ACHUNK - 1) / ACHUNK;
    int cap = (E_HG + NBUCK - 1) / NBUCK;
    cap = cap + cap / 4 + 64;
    cap = (cap + 63) & ~63;

    // ---- workspace layout (~135 MB; ws is ~1.6 GB) ----
    char* ws = (char*)d_ws;
    size_t off = 0;
    auto alloc = [&](size_t bytes) -> char* {
        char* p = ws + off;
        off += (bytes + 255) & ~(size_t)255;
        return p;
    };
    int*   cursor  = (int*)alloc((size_t)NBUCK * 4);
    int2*  bpair   = (int2*)alloc((size_t)NBUCK * cap * 8);
    int2*  ep      = (int2*)alloc((size_t)NBUCK * cap * 8 + 1024);
    int*   rp      = (int*)alloc((size_t)NHG * 4);
    int*   cnt     = (int*)alloc((size_t)NHG * 4);
    __hip_bfloat16* curA = (__hip_bfloat16*)alloc((size_t)NHG * 64 * 2);
    __hip_bfloat16* curB = (__hip_bfloat16*)alloc((size_t)NHG * 64 * 2);
    float* grp_acc = (float*)alloc((size_t)G_N * 64 * 4);
    float* gi_out  = (float*)alloc((size_t)G_N * 64 * 4);
    float* usr_acc = (float*)alloc((size_t)B_N * 64 * 4);
    short* Bfrag   = (short*)alloc((size_t)GG_KC * 4 * 64 * 8 * 2);
    float* gg_part = (float*)alloc((size_t)GG_SPLIT * GG_K * 64 * 4);
    (void)ws_size; (void)n_in; (void)out_size;

    // ---- P1: bfrag + cursor init ----
    k_phase1<<<GG_KC + 4, 256, 0, stream>>>(group_emb, Bfrag, cursor, cap, GG_KC);

    // ---- P2: bscatter || gg_mfma || cvt || ua/ga init || gi zero ----
    const int ggB  = GG_STRIPES * GG_SPLIT;  // 1256
    const int cvtB = (NHG * 16) / 256;       // 13125
    const int uaB  = (B_N * 64) / 256;       // 2048
    const int gaB  = (G_N * 64) / 256;       // 2500
    const int gzB  = (G_N * 64) / 256;       // 2500
    k_phase2<<<nblkA + ggB + cvtB + uaB + gaB + gzB, 256, 0, stream>>>(
        hg_rows, hg_cols, hg_vals, cursor, bpair, E_HG, cap,
        gg_graph, Bfrag, gg_part,
        (const float4*)user_emb, (const float4*)group_emb, (ushort4*)curB, ui,
        usr_acc, grp_acc, gi_out, nblkA, ggB, cvtB, uaB, gaB);

    // ---- P3: bcsr || gi_spmm ----
    const int giB = 2048;
    k_phase3<<<NBUCK + giB, 256, 0, stream>>>(cursor, bpair, ep, rp, cnt, cap,
                                              gi_rows, gi_cols, gi_vals,
                                              group_emb, item_emb, gi_out, E_GI, giB);

    const int spmmB = NHG / 16;              // 13125 exact
    const int uaExt = (B_N * 16) / 256;      // 512

    // P4: layer 1: curB -> curA (grp_acc fused)
    k_spmm4<<<spmmB, 256, 0, stream>>>(rp, cnt, ep, (const ushort4*)curB,
                                       (ushort4*)curA, grp_acc, nullptr, nullptr, spmmB);
    // P5: layer 2: curA -> curB (grp_acc fused; ext: usr_acc += curA[ui])
    k_spmm4<<<spmmB + uaExt, 256, 0, stream>>>(rp, cnt, ep, (const ushort4*)curA,
                                               (ushort4*)curB, grp_acc, ui, usr_acc, spmmB);
    // P6: layer 3 targeted; ext: usr_acc += curB[ui]
    const int taskB = (G_N + B_N + 15) / 16;  // 1137
    k_spmm4_final<<<taskB + uaExt, 256, 0, stream>>>(rp, cnt, ep, (const ushort4*)curB, ui,
                                                     grp_acc, usr_acc, taskB);

    // P7: fused finalize + gather
    k_gather_fin<<<B_N / 4, 256, 0, stream>>>(ui, pg, ng, usr_acc, grp_acc, gi_out, gg_part,
                                              hyper_w, hyper_b, lgcn_w, lgcn_b, ovl_w, ovl_b,
                                              user_emb, group_emb, (float*)d_out);
}